// Round 1
// baseline (814.641 us; speedup 1.0000x reference)
//
#include <hip/hip_runtime.h>
#include <math.h>

#define B_  8
#define C_  128
#define H_  128
#define W_  128
#define HW_ 16384

// ---- workspace layout (float offsets) ----
#define OFF_MPART 0          // [64 bblk][8 kc][256]      = 131072
#define OFF_SPART 131072     // [4 kind][1024 bc][8 kc]   = 32768
#define OFF_M     163840     // [64 bblk][256]            = 16384
#define OFF_S     180224     // [4 kind][1024 bc]         = 4096
#define OFF_COEF  184320     // aQ,bQ,aK,bK,aV,bV each 256 = 1536
#define OFF_WV    185856     // [8][16][16][16]           = 32768
#define OFF_CST   218624     // [8][256]                  = 2048
#define OFF_T     220672     // [8][128][9]               = 9216
#define OFF_WEFF  229888     // [8][9][128][128]          = 1179648

__device__ __forceinline__ float wave_sum64(float v) {
  v += __shfl_xor(v, 1);
  v += __shfl_xor(v, 2);
  v += __shfl_xor(v, 4);
  v += __shfl_xor(v, 8);
  v += __shfl_xor(v, 16);
  v += __shfl_xor(v, 32);
  return v;
}

// K1: per (b, blk, kc): M_part[16][16] = sum_p x[c0+i,p]*to[c0+j,p] over 2048 pixels,
// plus per-channel partial sums Sx,Sxx (x) and Sto,Stt (to).
__global__ __launch_bounds__(256) void k_reduce(const float* __restrict__ x,
                                                const float* __restrict__ to,
                                                float* __restrict__ ws) {
  const int bid  = blockIdx.x;            // 0..511
  const int kc   = bid & 7;
  const int blk  = (bid >> 3) & 7;
  const int b    = bid >> 6;
  const int wave = threadIdx.x >> 6;
  const int lane = threadIdx.x & 63;
  const int c0   = blk * 16;
  const int i0   = wave * 4;

  const float* xb = x  + ((size_t)b * C_ + c0) * HW_;
  const float* tb = to + ((size_t)b * C_ + c0) * HW_;

  float acc[4][16];
#pragma unroll
  for (int a = 0; a < 4; ++a)
#pragma unroll
    for (int j = 0; j < 16; ++j) acc[a][j] = 0.f;
  float sx[4] = {0,0,0,0}, sxx[4] = {0,0,0,0}, st[4] = {0,0,0,0}, stt[4] = {0,0,0,0};

  const int pbase = kc * 2048 + lane;
  for (int it = 0; it < 32; ++it) {
    const int p = pbase + it * 64;
    float tv[16];
#pragma unroll
    for (int j = 0; j < 16; ++j) tv[j] = tb[j * HW_ + p];
    float xv[4];
#pragma unroll
    for (int a = 0; a < 4; ++a) xv[a] = xb[(i0 + a) * HW_ + p];
#pragma unroll
    for (int a = 0; a < 4; ++a)
#pragma unroll
      for (int j = 0; j < 16; ++j) acc[a][j] = fmaf(xv[a], tv[j], acc[a][j]);
#pragma unroll
    for (int a = 0; a < 4; ++a) { sx[a] += xv[a]; sxx[a] = fmaf(xv[a], xv[a], sxx[a]); }
#pragma unroll
    for (int j = 0; j < 16; ++j)
      if ((j >> 2) == wave) { st[j & 3] += tv[j]; stt[j & 3] = fmaf(tv[j], tv[j], stt[j & 3]); }
  }

#pragma unroll
  for (int a = 0; a < 4; ++a) {
#pragma unroll
    for (int j = 0; j < 16; ++j) acc[a][j] = wave_sum64(acc[a][j]);
    sx[a]  = wave_sum64(sx[a]);
    sxx[a] = wave_sum64(sxx[a]);
    st[a]  = wave_sum64(st[a]);
    stt[a] = wave_sum64(stt[a]);
  }

  if (lane == 0) {
    float* Mp = ws + OFF_MPART + (size_t)((b * 8 + blk) * 8 + kc) * 256;
#pragma unroll
    for (int a = 0; a < 4; ++a)
#pragma unroll
      for (int j = 0; j < 16; ++j) Mp[(i0 + a) * 16 + j] = acc[a][j];
    float* Sp = ws + OFF_SPART;
#pragma unroll
    for (int a = 0; a < 4; ++a) {
      const int cidx = b * C_ + c0 + i0 + a;
      Sp[0 * 8192 + cidx * 8 + kc] = sx[a];
      Sp[1 * 8192 + cidx * 8 + kc] = sxx[a];
      Sp[2 * 8192 + cidx * 8 + kc] = st[a];
      Sp[3 * 8192 + cidx * 8 + kc] = stt[a];
    }
  }
}

// K2: single block. Phase A: fold affine chains -> aQ,bQ,aK,bK,aV,bV.
// Phase B: reduce partials. Phase C: norms, logits, softmax -> WV, cst.
__global__ __launch_bounds__(256) void k_setup(const float* __restrict__ t,
    const float* __restrict__ w_r1, const float* __restrict__ b_r1,
    const float* __restrict__ w_r2, const float* __restrict__ b_r2,
    const float* __restrict__ w_r3, const float* __restrict__ b_r3,
    const float* __restrict__ w_t1, const float* __restrict__ b_t1,
    const float* __restrict__ w_t2, const float* __restrict__ b_t2,
    const float* __restrict__ w_t3, const float* __restrict__ b_t3,
    float* __restrict__ ws) {
  const int tid = threadIdx.x;
  float* aQ = ws + OFF_COEF;
  float* bQ = aQ + 256;
  float* aK = bQ + 256;
  float* bK = aK + 256;
  float* aV = bK + 256;
  float* bV = aV + 256;

  if (tid < 128) {
    const int g = tid;
    float A1[4], B1[4], A2[2], B2[2];
    // rgb chain (Q)
#pragma unroll
    for (int j = 0; j < 4; ++j) { A1[j] = w_r1[g * 4 + j]; B1[j] = b_r1[g * 4 + j]; }
#pragma unroll
    for (int i = 0; i < 2; ++i) {
      A2[i] = 0.f; B2[i] = b_r2[g * 2 + i];
#pragma unroll
      for (int j = 0; j < 4; ++j) {
        const float w = w_r2[(g * 2 + i) * 4 + j];
        A2[i] = fmaf(w, A1[j], A2[i]); B2[i] = fmaf(w, B1[j], B2[i]);
      }
    }
#pragma unroll
    for (int o = 0; o < 2; ++o) {
      float a = 0.f, bb = b_r3[g * 2 + o];
#pragma unroll
      for (int i = 0; i < 2; ++i) {
        const float w = w_r3[(g * 2 + o) * 2 + i];
        a = fmaf(w, A2[i], a); bb = fmaf(w, B2[i], bb);
      }
      aQ[g * 2 + o] = a; bQ[g * 2 + o] = bb;
    }
    // text chain (K,V)
#pragma unroll
    for (int j = 0; j < 4; ++j) { A1[j] = w_t1[g * 4 + j]; B1[j] = b_t1[g * 4 + j]; }
#pragma unroll
    for (int i = 0; i < 2; ++i) {
      A2[i] = 0.f; B2[i] = b_t2[g * 2 + i];
#pragma unroll
      for (int j = 0; j < 4; ++j) {
        const float w = w_t2[(g * 2 + i) * 4 + j];
        A2[i] = fmaf(w, A1[j], A2[i]); B2[i] = fmaf(w, B1[j], B2[i]);
      }
    }
#pragma unroll
    for (int o = 0; o < 4; ++o) {
      float a = 0.f, bb = b_t3[g * 4 + o];
#pragma unroll
      for (int i = 0; i < 2; ++i) {
        const float w = w_t3[(g * 4 + o) * 2 + i];
        a = fmaf(w, A2[i], a); bb = fmaf(w, B2[i], bb);
      }
      if (o < 2) { aK[g * 2 + o] = a; bK[g * 2 + o] = bb; }
      else       { aV[g * 2 + (o - 2)] = a; bV[g * 2 + (o - 2)] = bb; }
    }
  }

  // Phase B: reduce partials
  float* M = ws + OFF_M;
  float* S = ws + OFF_S;
  for (int idx = tid; idx < 16384; idx += 256) {
    const float* mp = ws + OFF_MPART + (size_t)(idx >> 8) * 2048 + (idx & 255);
    float s = 0.f;
#pragma unroll
    for (int kcc = 0; kcc < 8; ++kcc) s += mp[kcc * 256];
    M[idx] = s;
  }
  for (int idx = tid; idx < 4096; idx += 256) {
    const float* sp = ws + OFF_SPART + (size_t)idx * 8;
    float s = 0.f;
#pragma unroll
    for (int kcc = 0; kcc < 8; ++kcc) s += sp[kcc];
    S[idx] = s;
  }
  __syncthreads();

  // Phase C
  if (tid < 128) {
    const int b = tid >> 4, h = tid & 15, e = h >> 3, blk = h & 7, c0 = blk * 16;
    const float* Sx  = S;
    const float* Sxx = S + 1024;
    const float* Sto = S + 2048;
    const float* Stt = S + 3072;
    float rnq[16], rnk[16], gA[16], gB[16], kA[16], kB[16];
#pragma unroll
    for (int i = 0; i < 16; ++i) {
      const int g = c0 + i;
      const float a = aQ[g * 2 + e], bb = bQ[g * 2 + e];
      gA[i] = a; gB[i] = bb;
      float s2 = a * a * Sxx[b * C_ + g] + 2.f * a * bb * Sx[b * C_ + g] + bb * bb * 16384.f;
      rnq[i] = 1.f / fmaxf(sqrtf(fmaxf(s2, 0.f)), 1e-12f);
    }
#pragma unroll
    for (int j = 0; j < 16; ++j) {
      const int g = c0 + j;
      const float a = aK[g * 2 + e], bb = bK[g * 2 + e];
      kA[j] = a; kB[j] = bb;
      float s2 = a * a * Stt[b * C_ + g] + 2.f * a * bb * Sto[b * C_ + g] + bb * bb * 16384.f;
      rnk[j] = 1.f / fmaxf(sqrtf(fmaxf(s2, 0.f)), 1e-12f);
    }
    const float tt = t[h];
    const float* Mrow = M + (b * 8 + blk) * 256;
    float* WVp = ws + OFF_WV + (size_t)(b * 16 + h) * 256;
    float* cst = ws + OFF_CST + b * 256;
#pragma unroll
    for (int i = 0; i < 16; ++i) {
      float lg[16];
      float mx = -1e30f;
      const float sxi = Sx[b * C_ + c0 + i];
#pragma unroll
      for (int j = 0; j < 16; ++j) {
        const float s = gA[i] * kA[j] * Mrow[i * 16 + j]
                      + gA[i] * kB[j] * sxi
                      + gB[i] * kA[j] * Sto[b * C_ + c0 + j]
                      + gB[i] * kB[j] * 16384.f;
        const float l = tt * s * rnq[i] * rnk[j];
        lg[j] = l;
        mx = fmaxf(mx, l);
      }
      float den = 0.f;
#pragma unroll
      for (int j = 0; j < 16; ++j) { const float ev = expf(lg[j] - mx); lg[j] = ev; den += ev; }
      const float inv = 1.f / den;
      float cs = 0.f;
#pragma unroll
      for (int j = 0; j < 16; ++j) {
        const float aa = lg[j] * inv;
        const int gj = c0 + j;
        WVp[i * 16 + j] = aa * aV[gj * 2 + e];
        cs = fmaf(aa, bV[gj * 2 + e], cs);
      }
      cst[i * 16 + h] = cs;  // cc = i*16 + h (d-major, head-minor)
    }
  }
}

// K3: per (b, oc): fold attention weights into per-batch conv weights
// w_eff[b][k][cin][oc], plus constant tap term T[b][oc][k].
__global__ __launch_bounds__(128) void k_weff(const float* __restrict__ w_f,
                                              float* __restrict__ ws) {
  const int b = blockIdx.x >> 7, oc = blockIdx.x & 127;
  const int c = threadIdx.x, blk = c >> 4, j = c & 15;
  const float* WVb = ws + OFF_WV;
  float acc[9];
#pragma unroll
  for (int k = 0; k < 9; ++k) acc[k] = 0.f;
#pragma unroll
  for (int e = 0; e < 2; ++e) {
    const int h = e * 8 + blk;
#pragma unroll
    for (int i = 0; i < 16; ++i) {
      const float coef = WVb[((size_t)(b * 16 + h) * 16 + i) * 16 + j];
      const float* wf = w_f + (size_t)(oc * 256 + i * 16 + h) * 9;
#pragma unroll
      for (int k = 0; k < 9; ++k) acc[k] = fmaf(wf[k], coef, acc[k]);
    }
  }
  float* weff = ws + OFF_WEFF;
#pragma unroll
  for (int k = 0; k < 9; ++k)
    weff[(((size_t)b * 9 + k) * 128 + c) * 128 + oc] = acc[k];

  // T[b][oc][k] = sum_cc w_f[oc,cc,k] * cst_cc[b,cc]
  __shared__ float tp[9][128];
  float tl[9];
#pragma unroll
  for (int k = 0; k < 9; ++k) tl[k] = 0.f;
  const float* cst = ws + OFF_CST + b * 256;
  for (int cc = c; cc < 256; cc += 128) {
    const float cv = cst[cc];
    const float* wf = w_f + (size_t)(oc * 256 + cc) * 9;
#pragma unroll
    for (int k = 0; k < 9; ++k) tl[k] = fmaf(wf[k], cv, tl[k]);
  }
#pragma unroll
  for (int k = 0; k < 9; ++k) tp[k][c] = tl[k];
  __syncthreads();
  for (int s = 64; s > 0; s >>= 1) {
    if (c < s) {
#pragma unroll
      for (int k = 0; k < 9; ++k) tp[k][c] += tp[k][c + s];
    }
    __syncthreads();
  }
  if (c < 9) ws[OFF_T + ((size_t)b * 128 + oc) * 9 + c] = tp[c][0];
}

// K4: per-batch 3x3 conv, Cin=128, Cout=128, over `to`, + constant taps (masked),
// + bias, LeakyReLU(0.2), residual add of x.
__global__ __launch_bounds__(256) void k_conv(const float* __restrict__ xin,
                                              const float* __restrict__ to,
                                              const float* __restrict__ b_f,
                                              const float* __restrict__ ws,
                                              float* __restrict__ out) {
  const int x0 = blockIdx.x * 64;
  const int y  = blockIdx.y;
  const int b  = blockIdx.z;
  const int tid = threadIdx.x;
  const int oc0 = (tid >> 4) * 8;
  const int px0 = (tid & 15) * 4;

  __shared__ float lds[64][3][68];

  float acc[8][4];
#pragma unroll
  for (int o = 0; o < 8; ++o)
#pragma unroll
    for (int p = 0; p < 4; ++p) acc[o][p] = 0.f;

  const float* weffb = ws + OFF_WEFF + (size_t)b * 9 * 128 * 128;
  const float* tob   = to + (size_t)b * C_ * HW_;

  for (int cb = 0; cb < 128; cb += 64) {
    __syncthreads();
    for (int idx = tid; idx < 64 * 198; idx += 256) {
      const int c  = idx / 198;
      const int r  = idx - c * 198;
      const int dy = r / 66;
      const int xi = r - dy * 66;
      const int yy = y + dy - 1;
      const int xx = x0 + xi - 1;
      float v = 0.f;
      if (yy >= 0 && yy < H_ && xx >= 0 && xx < W_)
        v = tob[(size_t)(cb + c) * HW_ + yy * W_ + xx];
      lds[c][dy][xi] = v;
    }
    __syncthreads();

    for (int c = 0; c < 64; ++c) {
      const float* wp = weffb + (size_t)(cb + c) * 128 + oc0;
#pragma unroll
      for (int dy = 0; dy < 3; ++dy) {
        const float4 ta = *(const float4*)&lds[c][dy][px0];
        const float t4 = lds[c][dy][px0 + 4];
        const float t5 = lds[c][dy][px0 + 5];
        const float tvv[6] = {ta.x, ta.y, ta.z, ta.w, t4, t5};
#pragma unroll
        for (int kx = 0; kx < 3; ++kx) {
          const int k = dy * 3 + kx;
          const float4 w0 = *(const float4*)(wp + (size_t)k * 16384);
          const float4 w1 = *(const float4*)(wp + (size_t)k * 16384 + 4);
          const float u0 = tvv[kx + 0], u1 = tvv[kx + 1], u2 = tvv[kx + 2], u3 = tvv[kx + 3];
#define FMA4(WW, OO) \
  acc[OO][0] = fmaf(WW, u0, acc[OO][0]); acc[OO][1] = fmaf(WW, u1, acc[OO][1]); \
  acc[OO][2] = fmaf(WW, u2, acc[OO][2]); acc[OO][3] = fmaf(WW, u3, acc[OO][3]);
          FMA4(w0.x, 0) FMA4(w0.y, 1) FMA4(w0.z, 2) FMA4(w0.w, 3)
          FMA4(w1.x, 4) FMA4(w1.y, 5) FMA4(w1.z, 6) FMA4(w1.w, 7)
#undef FMA4
        }
      }
    }
  }

  // epilogue: constant-tap term (border-masked), bias, leaky, residual
  const bool v0 = (y >= 1), v2 = (y <= 126);
  const float* Tb = ws + OFF_T + (size_t)(b * 128) * 9;
  const int xgbase = x0 + px0;
#pragma unroll
  for (int oo = 0; oo < 8; ++oo) {
    const float* Tk = Tb + (size_t)(oc0 + oo) * 9;
    float s = Tk[3] + Tk[4] + Tk[5];
    float sL = Tk[3], sR = Tk[5];
    if (v0) { s += Tk[0] + Tk[1] + Tk[2]; sL += Tk[0]; sR += Tk[2]; }
    if (v2) { s += Tk[6] + Tk[7] + Tk[8]; sL += Tk[6]; sR += Tk[8]; }
    const float bf = b_f[oc0 + oo];
    const size_t base = ((size_t)(b * C_ + oc0 + oo)) * HW_ + (size_t)y * W_ + xgbase;
    const float4 rx = *(const float4*)(xin + base);
    float4 r;
    {
      float add = s; if (xgbase + 0 == 0) add -= sL; if (xgbase + 0 == 127) add -= sR;
      float z = acc[oo][0] + add + bf; r.x = rx.x + (z >= 0.f ? z : 0.2f * z);
    }
    {
      float add = s; if (xgbase + 1 == 0) add -= sL; if (xgbase + 1 == 127) add -= sR;
      float z = acc[oo][1] + add + bf; r.y = rx.y + (z >= 0.f ? z : 0.2f * z);
    }
    {
      float add = s; if (xgbase + 2 == 0) add -= sL; if (xgbase + 2 == 127) add -= sR;
      float z = acc[oo][2] + add + bf; r.z = rx.z + (z >= 0.f ? z : 0.2f * z);
    }
    {
      float add = s; if (xgbase + 3 == 0) add -= sL; if (xgbase + 3 == 127) add -= sR;
      float z = acc[oo][3] + add + bf; r.w = rx.w + (z >= 0.f ? z : 0.2f * z);
    }
    *(float4*)(out + base) = r;
  }
}

extern "C" void kernel_launch(void* const* d_in, const int* in_sizes, int n_in,
                              void* d_out, int out_size, void* d_ws, size_t ws_size,
                              hipStream_t stream) {
  (void)in_sizes; (void)n_in; (void)out_size; (void)ws_size;
  const float* x    = (const float*)d_in[0];
  const float* to   = (const float*)d_in[1];
  const float* t    = (const float*)d_in[2];
  const float* w_r1 = (const float*)d_in[3];
  const float* b_r1 = (const float*)d_in[4];
  const float* w_r2 = (const float*)d_in[5];
  const float* b_r2 = (const float*)d_in[6];
  const float* w_r3 = (const float*)d_in[7];
  const float* b_r3 = (const float*)d_in[8];
  const float* w_t1 = (const float*)d_in[9];
  const float* b_t1 = (const float*)d_in[10];
  const float* w_t2 = (const float*)d_in[11];
  const float* b_t2 = (const float*)d_in[12];
  const float* w_t3 = (const float*)d_in[13];
  const float* b_t3 = (const float*)d_in[14];
  const float* w_f  = (const float*)d_in[15];
  const float* b_f  = (const float*)d_in[16];
  float* ws  = (float*)d_ws;
  float* out = (float*)d_out;

  k_reduce<<<512, 256, 0, stream>>>(x, to, ws);
  k_setup<<<1, 256, 0, stream>>>(t, w_r1, b_r1, w_r2, b_r2, w_r3, b_r3,
                                 w_t1, b_t1, w_t2, b_t2, w_t3, b_t3, ws);
  k_weff<<<1024, 128, 0, stream>>>(w_f, ws);
  dim3 g4(2, 128, 8);
  k_conv<<<g4, 256, 0, stream>>>(x, to, b_f, ws, out);
}

// Round 2
// 440.443 us; speedup vs baseline: 1.8496x; 1.8496x over previous
//
#include <hip/hip_runtime.h>
#include <math.h>

#define B_  8
#define C_  128
#define H_  128
#define W_  128
#define HW_ 16384

// ---- workspace layout (float offsets) ----
#define OFF_MPART 0          // [64 bblk][8 kc][256]      = 131072
#define OFF_SPART 131072     // [4 kind][1024 bc][8 kc]   = 32768
#define OFF_M     163840     // [64 bblk][256]            = 16384
#define OFF_S     180224     // [4 kind][1024 bc]         = 4096
#define OFF_WV    185856     // [8][16][16][16]           = 32768
#define OFF_CST   218624     // [8][256]                  = 2048
#define OFF_T     220672     // [8][128][9]               = 9216
#define OFF_WEFF  229888     // bf16 [8][9 tap][128 oc][128 cin] = 1179648 ushort

typedef __attribute__((ext_vector_type(8))) short short8;
typedef __attribute__((ext_vector_type(4))) float f32x4;

__device__ __forceinline__ unsigned short f2bf(float f) {
  unsigned u = __float_as_uint(f);
  u += 0x7fffu + ((u >> 16) & 1u);
  return (unsigned short)(u >> 16);
}

__device__ __forceinline__ f32x4 mfma16(short8 a, short8 b, f32x4 c) {
  return __builtin_amdgcn_mfma_f32_16x16x32_bf16(a, b, c, 0, 0, 0);
}

__device__ __forceinline__ float wave_sum64(float v) {
  v += __shfl_xor(v, 1);
  v += __shfl_xor(v, 2);
  v += __shfl_xor(v, 4);
  v += __shfl_xor(v, 8);
  v += __shfl_xor(v, 16);
  v += __shfl_xor(v, 32);
  return v;
}

// K1: per (b, blk, kc): M_part[16][16] = sum_p x[c0+i,p]*to[c0+j,p] over 2048 pixels,
// plus per-channel partial sums Sx,Sxx (x) and Sto,Stt (to).
__global__ __launch_bounds__(256) void k_reduce(const float* __restrict__ x,
                                                const float* __restrict__ to,
                                                float* __restrict__ ws) {
  const int bid  = blockIdx.x;            // 0..511
  const int kc   = bid & 7;
  const int blk  = (bid >> 3) & 7;
  const int b    = bid >> 6;
  const int wave = threadIdx.x >> 6;
  const int lane = threadIdx.x & 63;
  const int c0   = blk * 16;
  const int i0   = wave * 4;

  const float* xb = x  + ((size_t)b * C_ + c0) * HW_;
  const float* tb = to + ((size_t)b * C_ + c0) * HW_;

  float acc[4][16];
#pragma unroll
  for (int a = 0; a < 4; ++a)
#pragma unroll
    for (int j = 0; j < 16; ++j) acc[a][j] = 0.f;
  float sx[4] = {0,0,0,0}, sxx[4] = {0,0,0,0}, st[4] = {0,0,0,0}, stt[4] = {0,0,0,0};

  const int pbase = kc * 2048 + lane;
  for (int it = 0; it < 32; ++it) {
    const int p = pbase + it * 64;
    float tv[16];
#pragma unroll
    for (int j = 0; j < 16; ++j) tv[j] = tb[j * HW_ + p];
    float xv[4];
#pragma unroll
    for (int a = 0; a < 4; ++a) xv[a] = xb[(i0 + a) * HW_ + p];
#pragma unroll
    for (int a = 0; a < 4; ++a)
#pragma unroll
      for (int j = 0; j < 16; ++j) acc[a][j] = fmaf(xv[a], tv[j], acc[a][j]);
#pragma unroll
    for (int a = 0; a < 4; ++a) { sx[a] += xv[a]; sxx[a] = fmaf(xv[a], xv[a], sxx[a]); }
#pragma unroll
    for (int j = 0; j < 16; ++j)
      if ((j >> 2) == wave) { st[j & 3] += tv[j]; stt[j & 3] = fmaf(tv[j], tv[j], stt[j & 3]); }
  }

#pragma unroll
  for (int a = 0; a < 4; ++a) {
#pragma unroll
    for (int j = 0; j < 16; ++j) acc[a][j] = wave_sum64(acc[a][j]);
    sx[a]  = wave_sum64(sx[a]);
    sxx[a] = wave_sum64(sxx[a]);
    st[a]  = wave_sum64(st[a]);
    stt[a] = wave_sum64(stt[a]);
  }

  if (lane == 0) {
    float* Mp = ws + OFF_MPART + (size_t)((b * 8 + blk) * 8 + kc) * 256;
#pragma unroll
    for (int a = 0; a < 4; ++a)
#pragma unroll
      for (int j = 0; j < 16; ++j) Mp[(i0 + a) * 16 + j] = acc[a][j];
    float* Sp = ws + OFF_SPART;
#pragma unroll
    for (int a = 0; a < 4; ++a) {
      const int cidx = b * C_ + c0 + i0 + a;
      Sp[0 * 8192 + cidx * 8 + kc] = sx[a];
      Sp[1 * 8192 + cidx * 8 + kc] = sxx[a];
      Sp[2 * 8192 + cidx * 8 + kc] = st[a];
      Sp[3 * 8192 + cidx * 8 + kc] = stt[a];
    }
  }
}

// K1b: parallel reduction of partials (was phase B of k_setup).
__global__ __launch_bounds__(256) void k_redB(float* __restrict__ ws) {
  const int gid = blockIdx.x * 256 + threadIdx.x;   // 80*256 = 20480
  if (gid < 16384) {
    const float* mp = ws + OFF_MPART + (size_t)(gid >> 8) * 2048 + (gid & 255);
    float s = 0.f;
#pragma unroll
    for (int kc = 0; kc < 8; ++kc) s += mp[kc * 256];
    ws[OFF_M + gid] = s;
  } else {
    const int sidx = gid - 16384;
    const float* sp = ws + OFF_SPART + (size_t)sidx * 8;
    float s = 0.f;
#pragma unroll
    for (int kc = 0; kc < 8; ++kc) s += sp[kc];
    ws[OFF_S + sidx] = s;
  }
}

// K2: single block. Phase A: fold affine chains -> coef (shared).
// Phase C: norms, logits, softmax -> WV, cst.
__global__ __launch_bounds__(256) void k_setup(const float* __restrict__ t,
    const float* __restrict__ w_r1, const float* __restrict__ b_r1,
    const float* __restrict__ w_r2, const float* __restrict__ b_r2,
    const float* __restrict__ w_r3, const float* __restrict__ b_r3,
    const float* __restrict__ w_t1, const float* __restrict__ b_t1,
    const float* __restrict__ w_t2, const float* __restrict__ b_t2,
    const float* __restrict__ w_t3, const float* __restrict__ b_t3,
    float* __restrict__ ws) {
  const int tid = threadIdx.x;
  __shared__ float aQ[256], bQ[256], aK[256], bK[256], aV[256], bV[256];

  if (tid < 128) {
    const int g = tid;
    float A1[4], B1[4], A2[2], B2[2];
    // rgb chain (Q)
#pragma unroll
    for (int j = 0; j < 4; ++j) { A1[j] = w_r1[g * 4 + j]; B1[j] = b_r1[g * 4 + j]; }
#pragma unroll
    for (int i = 0; i < 2; ++i) {
      A2[i] = 0.f; B2[i] = b_r2[g * 2 + i];
#pragma unroll
      for (int j = 0; j < 4; ++j) {
        const float w = w_r2[(g * 2 + i) * 4 + j];
        A2[i] = fmaf(w, A1[j], A2[i]); B2[i] = fmaf(w, B1[j], B2[i]);
      }
    }
#pragma unroll
    for (int o = 0; o < 2; ++o) {
      float a = 0.f, bb = b_r3[g * 2 + o];
#pragma unroll
      for (int i = 0; i < 2; ++i) {
        const float w = w_r3[(g * 2 + o) * 2 + i];
        a = fmaf(w, A2[i], a); bb = fmaf(w, B2[i], bb);
      }
      aQ[g * 2 + o] = a; bQ[g * 2 + o] = bb;
    }
    // text chain (K,V)
#pragma unroll
    for (int j = 0; j < 4; ++j) { A1[j] = w_t1[g * 4 + j]; B1[j] = b_t1[g * 4 + j]; }
#pragma unroll
    for (int i = 0; i < 2; ++i) {
      A2[i] = 0.f; B2[i] = b_t2[g * 2 + i];
#pragma unroll
      for (int j = 0; j < 4; ++j) {
        const float w = w_t2[(g * 2 + i) * 4 + j];
        A2[i] = fmaf(w, A1[j], A2[i]); B2[i] = fmaf(w, B1[j], B2[i]);
      }
    }
#pragma unroll
    for (int o = 0; o < 4; ++o) {
      float a = 0.f, bb = b_t3[g * 4 + o];
#pragma unroll
      for (int i = 0; i < 2; ++i) {
        const float w = w_t3[(g * 4 + o) * 2 + i];
        a = fmaf(w, A2[i], a); bb = fmaf(w, B2[i], bb);
      }
      if (o < 2) { aK[g * 2 + o] = a; bK[g * 2 + o] = bb; }
      else       { aV[g * 2 + (o - 2)] = a; bV[g * 2 + (o - 2)] = bb; }
    }
  }
  __syncthreads();

  // Phase C
  const float* M = ws + OFF_M;
  const float* S = ws + OFF_S;
  if (tid < 128) {
    const int b = tid >> 4, h = tid & 15, e = h >> 3, blk = h & 7, c0 = blk * 16;
    const float* Sx  = S;
    const float* Sxx = S + 1024;
    const float* Sto = S + 2048;
    const float* Stt = S + 3072;
    float rnq[16], rnk[16], gA[16], gB[16], kA[16], kB[16];
#pragma unroll
    for (int i = 0; i < 16; ++i) {
      const int g = c0 + i;
      const float a = aQ[g * 2 + e], bb = bQ[g * 2 + e];
      gA[i] = a; gB[i] = bb;
      float s2 = a * a * Sxx[b * C_ + g] + 2.f * a * bb * Sx[b * C_ + g] + bb * bb * 16384.f;
      rnq[i] = 1.f / fmaxf(sqrtf(fmaxf(s2, 0.f)), 1e-12f);
    }
#pragma unroll
    for (int j = 0; j < 16; ++j) {
      const int g = c0 + j;
      const float a = aK[g * 2 + e], bb = bK[g * 2 + e];
      kA[j] = a; kB[j] = bb;
      float s2 = a * a * Stt[b * C_ + g] + 2.f * a * bb * Sto[b * C_ + g] + bb * bb * 16384.f;
      rnk[j] = 1.f / fmaxf(sqrtf(fmaxf(s2, 0.f)), 1e-12f);
    }
    const float tt = t[h];
    const float* Mrow = M + (b * 8 + blk) * 256;
    float* WVp = ws + OFF_WV + (size_t)(b * 16 + h) * 256;
    float* cst = ws + OFF_CST + b * 256;
#pragma unroll
    for (int i = 0; i < 16; ++i) {
      float lg[16];
      float mx = -1e30f;
      const float sxi = Sx[b * C_ + c0 + i];
#pragma unroll
      for (int j = 0; j < 16; ++j) {
        const float s = gA[i] * kA[j] * Mrow[i * 16 + j]
                      + gA[i] * kB[j] * sxi
                      + gB[i] * kA[j] * Sto[b * C_ + c0 + j]
                      + gB[i] * kB[j] * 16384.f;
        const float l = tt * s * rnq[i] * rnk[j];
        lg[j] = l;
        mx = fmaxf(mx, l);
      }
      float den = 0.f;
#pragma unroll
      for (int j = 0; j < 16; ++j) { const float ev = expf(lg[j] - mx); lg[j] = ev; den += ev; }
      const float inv = 1.f / den;
      float cs = 0.f;
#pragma unroll
      for (int j = 0; j < 16; ++j) {
        const float aa = lg[j] * inv;
        const int gj = c0 + j;
        WVp[i * 16 + j] = aa * aV[gj * 2 + e];
        cs = fmaf(aa, bV[gj * 2 + e], cs);
      }
      cst[i * 16 + h] = cs;  // cc = i*16 + h (d-major, head-minor)
    }
  }
}

// K3: per (b, oc): fold attention weights into per-batch bf16 conv weights
// wb16[b][tap][oc][cin], plus constant tap term T[b][oc][k].
__global__ __launch_bounds__(128) void k_weff(const float* __restrict__ w_f,
                                              float* __restrict__ ws) {
  const int b = blockIdx.x >> 7, oc = blockIdx.x & 127;
  const int c = threadIdx.x, blk = c >> 4, j = c & 15;
  const float* WVb = ws + OFF_WV;
  float acc[9];
#pragma unroll
  for (int k = 0; k < 9; ++k) acc[k] = 0.f;
#pragma unroll
  for (int e = 0; e < 2; ++e) {
    const int h = e * 8 + blk;
#pragma unroll
    for (int i = 0; i < 16; ++i) {
      const float coef = WVb[((size_t)(b * 16 + h) * 16 + i) * 16 + j];
      const float* wf = w_f + (size_t)(oc * 256 + i * 16 + h) * 9;
#pragma unroll
      for (int k = 0; k < 9; ++k) acc[k] = fmaf(wf[k], coef, acc[k]);
    }
  }
  unsigned short* wb16 = (unsigned short*)(ws + OFF_WEFF);
#pragma unroll
  for (int k = 0; k < 9; ++k)
    wb16[(((size_t)(b * 9 + k)) * 128 + oc) * 128 + c] = f2bf(acc[k]);

  // T[b][oc][k] = sum_cc w_f[oc,cc,k] * cst_cc[b,cc]
  __shared__ float tp[9][128];
  float tl[9];
#pragma unroll
  for (int k = 0; k < 9; ++k) tl[k] = 0.f;
  const float* cst = ws + OFF_CST + b * 256;
  for (int cc = c; cc < 256; cc += 128) {
    const float cv = cst[cc];
    const float* wf = w_f + (size_t)(oc * 256 + cc) * 9;
#pragma unroll
    for (int k = 0; k < 9; ++k) tl[k] = fmaf(wf[k], cv, tl[k]);
  }
#pragma unroll
  for (int k = 0; k < 9; ++k) tp[k][c] = tl[k];
  __syncthreads();
  for (int s = 64; s > 0; s >>= 1) {
    if (c < s) {
#pragma unroll
      for (int k = 0; k < 9; ++k) tp[k][c] += tp[k][c + s];
    }
    __syncthreads();
  }
  if (c < 9) ws[OFF_T + ((size_t)b * 128 + oc) * 9 + c] = tp[c][0];
}

// K4: per-batch bf16 MFMA conv. One block per (b, y). 8 waves, each 64oc x 32px.
// LDS: to-tile [3 rows][130 x][64 cin] bf16, transposed + XOR-swizzled.
__global__ __launch_bounds__(512, 4) void k_conv(const float* __restrict__ xin,
                                                 const float* __restrict__ to,
                                                 const float* __restrict__ b_f,
                                                 const float* __restrict__ ws,
                                                 float* __restrict__ out) {
  const int bid = blockIdx.x;
  const int nb  = (bid & 7) * 128 + (bid >> 3);   // XCD swizzle: batch per XCD
  const int b   = nb >> 7;
  const int y   = nb & 127;
  const int tid = threadIdx.x;

  __shared__ f32x4 ldsbuf[3120];   // 49920 B = 3*130*128
  char* lp = (char*)ldsbuf;

  f32x4 acc[4][2];
#pragma unroll
  for (int mt = 0; mt < 4; ++mt)
#pragma unroll
    for (int nt = 0; nt < 2; ++nt) acc[mt][nt] = (f32x4)0.f;

  const float* tob = to + (size_t)b * C_ * HW_;
  const unsigned short* wb16 =
      (const unsigned short*)(ws + OFF_WEFF) + (size_t)b * 9 * 128 * 128;

  const int l = tid & 63, wv = tid >> 6;
  const int ocb0 = (wv & 1) * 64, pxb0 = (wv >> 1) * 32;
  const int lm = l & 15, lh = l >> 4;

  for (int cb = 0; cb < 128; cb += 64) {
    __syncthreads();
    {
      const int xg = tid & 31, cq = (tid >> 5) & 15;
      const int cbase = cb + cq * 4;
#pragma unroll
      for (int row = 0; row < 3; ++row) {
        const int y_in = y + row - 1;
        const bool yok = ((unsigned)y_in < 128u);
        const float* src = tob + (size_t)cbase * HW_ + (size_t)y_in * W_;
#pragma unroll
        for (int xb = 0; xb < 5; ++xb) {
          const int xi = xb * 32 + xg;
          if (xi < 130) {
            const int x_in = xi - 1;
            const bool ok = yok && ((unsigned)x_in < 128u);
            float f0 = 0.f, f1 = 0.f, f2 = 0.f, f3 = 0.f;
            if (ok) {
              f0 = src[x_in];
              f1 = src[HW_ + x_in];
              f2 = src[2 * HW_ + x_in];
              f3 = src[3 * HW_ + x_in];
            }
            ushort4 pk;
            pk.x = f2bf(f0); pk.y = f2bf(f1); pk.z = f2bf(f2); pk.w = f2bf(f3);
            const int boff = (row * 130 + xi) * 128 + ((cq * 8) ^ ((xi & 7) << 4));
            *(ushort4*)(lp + boff) = pk;
          }
        }
      }
    }
    __syncthreads();

    for (int tap = 0; tap < 9; ++tap) {
      const int dy = tap / 3, dx = tap - dy * 3;
#pragma unroll
      for (int ks = 0; ks < 2; ++ks) {
        short8 bfr[2];
#pragma unroll
        for (int nt = 0; nt < 2; ++nt) {
          const int xi = pxb0 + nt * 16 + lm + dx;
          const int boff = (dy * 130 + xi) * 128 + ((ks * 64 + lh * 16) ^ ((xi & 7) << 4));
          bfr[nt] = *(const short8*)(lp + boff);
        }
        const int cin = cb + ks * 32 + lh * 8;
#pragma unroll
        for (int mt = 0; mt < 4; ++mt) {
          const int oc = ocb0 + mt * 16 + lm;
          const short8 af = *(const short8*)(wb16 + ((size_t)tap * 128 + oc) * 128 + cin);
          acc[mt][0] = mfma16(af, bfr[0], acc[mt][0]);
          acc[mt][1] = mfma16(af, bfr[1], acc[mt][1]);
        }
      }
    }
  }

  // epilogue: per-oc constant terms into LDS, then masked add + leaky + residual
  __syncthreads();
  float* sAdd = (float*)ldsbuf;
  float* sLft = sAdd + 128;
  float* sRgt = sAdd + 256;
  if (tid < 128) {
    const float* Tk = ws + OFF_T + (size_t)(b * 128 + tid) * 9;
    float s = Tk[3] + Tk[4] + Tk[5], sl = Tk[3], sr = Tk[5];
    if (y >= 1)   { s += Tk[0] + Tk[1] + Tk[2]; sl += Tk[0]; sr += Tk[2]; }
    if (y <= 126) { s += Tk[6] + Tk[7] + Tk[8]; sl += Tk[6]; sr += Tk[8]; }
    sAdd[tid] = s + b_f[tid]; sLft[tid] = sl; sRgt[tid] = sr;
  }
  __syncthreads();

#pragma unroll
  for (int mt = 0; mt < 4; ++mt)
#pragma unroll
    for (int nt = 0; nt < 2; ++nt) {
      const int px = pxb0 + nt * 16 + lm;
#pragma unroll
      for (int r = 0; r < 4; ++r) {
        const int oc = ocb0 + mt * 16 + lh * 4 + r;
        float add = sAdd[oc];
        if (px == 0)   add -= sLft[oc];
        if (px == 127) add -= sRgt[oc];
        const float z = acc[mt][nt][r] + add;
        const size_t base = ((size_t)(b * C_ + oc)) * HW_ + (size_t)y * W_ + px;
        const float rx = xin[base];
        out[base] = rx + (z >= 0.f ? z : 0.2f * z);
      }
    }
}

extern "C" void kernel_launch(void* const* d_in, const int* in_sizes, int n_in,
                              void* d_out, int out_size, void* d_ws, size_t ws_size,
                              hipStream_t stream) {
  (void)in_sizes; (void)n_in; (void)out_size; (void)ws_size;
  const float* x    = (const float*)d_in[0];
  const float* to   = (const float*)d_in[1];
  const float* t    = (const float*)d_in[2];
  const float* w_r1 = (const float*)d_in[3];
  const float* b_r1 = (const float*)d_in[4];
  const float* w_r2 = (const float*)d_in[5];
  const float* b_r2 = (const float*)d_in[6];
  const float* w_r3 = (const float*)d_in[7];
  const float* b_r3 = (const float*)d_in[8];
  const float* w_t1 = (const float*)d_in[9];
  const float* b_t1 = (const float*)d_in[10];
  const float* w_t2 = (const float*)d_in[11];
  const float* b_t2 = (const float*)d_in[12];
  const float* w_t3 = (const float*)d_in[13];
  const float* b_t3 = (const float*)d_in[14];
  const float* w_f  = (const float*)d_in[15];
  const float* b_f  = (const float*)d_in[16];
  float* ws  = (float*)d_ws;
  float* out = (float*)d_out;

  k_reduce<<<512, 256, 0, stream>>>(x, to, ws);
  k_redB<<<80, 256, 0, stream>>>(ws);
  k_setup<<<1, 256, 0, stream>>>(t, w_r1, b_r1, w_r2, b_r2, w_r3, b_r3,
                                 w_t1, b_t1, w_t2, b_t2, w_t3, b_t3, ws);
  k_weff<<<1024, 128, 0, stream>>>(w_f, ws);
  k_conv<<<1024, 512, 0, stream>>>(x, to, b_f, ws, out);
}

// Round 3
// 380.362 us; speedup vs baseline: 2.1418x; 1.1580x over previous
//
#include <hip/hip_runtime.h>
#include <math.h>

#define B_  8
#define C_  128
#define H_  128
#define W_  128
#define HW_ 16384

// ---- workspace layout (float offsets) ----
#define OFF_MPART 0          // [64 bblk][16 kc][256]     = 262144
#define OFF_SPART 262144     // [4 kind][1024 bc][16 kc]  = 65536
#define OFF_M     327680     // [64 bblk][256]            = 16384
#define OFF_S     344064     // [4 kind][1024 bc]         = 4096
#define OFF_WV    348160     // [8][16][16][16]           = 32768
#define OFF_CST   380928     // [8][256]                  = 2048
#define OFF_T     382976     // [8][128][9]               = 9216
#define OFF_WEFF  392192     // bf16 [8][9 tap][128 oc][128 cin] = 1179648 ushort = 589824 fl
#define OFF_T2F   982016     // bf16 T2 [8][128 y][130 x'][128 c] = 17039360 ushort
#define WS_NEED   (982016ull * 4ull + 34078720ull)

typedef __attribute__((ext_vector_type(8))) short short8;
typedef __attribute__((ext_vector_type(4))) float f32x4;

__device__ __forceinline__ unsigned short f2bf(float f) {
  unsigned u = __float_as_uint(f);
  u += 0x7fffu + ((u >> 16) & 1u);
  return (unsigned short)(u >> 16);
}

__device__ __forceinline__ f32x4 mfma16(short8 a, short8 b, f32x4 c) {
  return __builtin_amdgcn_mfma_f32_16x16x32_bf16(a, b, c, 0, 0, 0);
}

__device__ __forceinline__ float wave_sum64(float v) {
  v += __shfl_xor(v, 1);
  v += __shfl_xor(v, 2);
  v += __shfl_xor(v, 4);
  v += __shfl_xor(v, 8);
  v += __shfl_xor(v, 16);
  v += __shfl_xor(v, 32);
  return v;
}

// K1: per (b, blk, kc16): M_part[16][16] over 1024 px + per-channel partial moments.
__global__ __launch_bounds__(256) void k_reduce(const float* __restrict__ x,
                                                const float* __restrict__ to,
                                                float* __restrict__ ws) {
  const int bid  = blockIdx.x;            // 0..1023
  const int kc   = bid & 15;
  const int blk  = (bid >> 4) & 7;
  const int b    = bid >> 7;
  const int wave = threadIdx.x >> 6;
  const int lane = threadIdx.x & 63;
  const int c0   = blk * 16;
  const int i0   = wave * 4;

  const float* xb = x  + ((size_t)b * C_ + c0) * HW_;
  const float* tb = to + ((size_t)b * C_ + c0) * HW_;

  float acc[4][16];
#pragma unroll
  for (int a = 0; a < 4; ++a)
#pragma unroll
    for (int j = 0; j < 16; ++j) acc[a][j] = 0.f;
  float sx[4] = {0,0,0,0}, sxx[4] = {0,0,0,0}, st[4] = {0,0,0,0}, stt[4] = {0,0,0,0};

  const int pbase = kc * 1024 + lane;
#pragma unroll 1
  for (int it = 0; it < 16; ++it) {
    const int p = pbase + it * 64;
    float tv[16];
#pragma unroll
    for (int j = 0; j < 16; ++j) tv[j] = tb[j * HW_ + p];
    float xv[4];
#pragma unroll
    for (int a = 0; a < 4; ++a) xv[a] = xb[(i0 + a) * HW_ + p];
#pragma unroll
    for (int a = 0; a < 4; ++a)
#pragma unroll
      for (int j = 0; j < 16; ++j) acc[a][j] = fmaf(xv[a], tv[j], acc[a][j]);
#pragma unroll
    for (int a = 0; a < 4; ++a) { sx[a] += xv[a]; sxx[a] = fmaf(xv[a], xv[a], sxx[a]); }
#pragma unroll
    for (int j = 0; j < 16; ++j)
      if ((j >> 2) == wave) { st[j & 3] += tv[j]; stt[j & 3] = fmaf(tv[j], tv[j], stt[j & 3]); }
  }

#pragma unroll
  for (int a = 0; a < 4; ++a) {
#pragma unroll
    for (int j = 0; j < 16; ++j) acc[a][j] = wave_sum64(acc[a][j]);
    sx[a]  = wave_sum64(sx[a]);
    sxx[a] = wave_sum64(sxx[a]);
    st[a]  = wave_sum64(st[a]);
    stt[a] = wave_sum64(stt[a]);
  }

  if (lane == 0) {
    float* Mp = ws + OFF_MPART + (size_t)((b * 8 + blk) * 16 + kc) * 256;
#pragma unroll
    for (int a = 0; a < 4; ++a)
#pragma unroll
      for (int j = 0; j < 16; ++j) Mp[(i0 + a) * 16 + j] = acc[a][j];
    float* Sp = ws + OFF_SPART;
#pragma unroll
    for (int a = 0; a < 4; ++a) {
      const int cidx = b * C_ + c0 + i0 + a;
      Sp[0 * 16384 + cidx * 16 + kc] = sx[a];
      Sp[1 * 16384 + cidx * 16 + kc] = sxx[a];
      Sp[2 * 16384 + cidx * 16 + kc] = st[a];
      Sp[3 * 16384 + cidx * 16 + kc] = stt[a];
    }
  }
}

// K1b: parallel reduction of partials.
__global__ __launch_bounds__(256) void k_redB(float* __restrict__ ws) {
  const int gid = blockIdx.x * 256 + threadIdx.x;   // 80*256 = 20480
  if (gid < 16384) {
    const float* mp = ws + OFF_MPART + (size_t)(gid >> 8) * 4096 + (gid & 255);
    float s = 0.f;
#pragma unroll
    for (int kc = 0; kc < 16; ++kc) s += mp[kc * 256];
    ws[OFF_M + gid] = s;
  } else {
    const int sidx = gid - 16384;
    const float* sp = ws + OFF_SPART + (size_t)sidx * 16;
    float s = 0.f;
#pragma unroll
    for (int kc = 0; kc < 16; ++kc) s += sp[kc];
    ws[OFF_S + sidx] = s;
  }
}

// K_tr: transpose to -> bf16 T2[b][y][x'][c], x' = x+1, zero-padded x'=0/129.
__global__ __launch_bounds__(256) void k_tr(const float* __restrict__ to,
                                            unsigned short* __restrict__ t2) {
  const int d  = blockIdx.x;          // 2048 = xh(2) * y(128) * b(8)
  const int xh = d & 1;
  const int y  = (d >> 1) & 127;
  const int b  = d >> 8;
  const int tid = threadIdx.x;
  __shared__ char lds[64 * 256];      // 16 KB

  const int x0 = xh * 64;
  const int xl = tid & 63;
  const int cg = tid >> 6;            // 0..3
  const float* src = to + ((size_t)b * C_) * HW_ + (size_t)y * W_ + x0 + xl;
#pragma unroll
  for (int k = 0; k < 32; ++k) {
    const int c = cg * 32 + k;
    const float v = src[(size_t)c * HW_];
    const int boff = xl * 256 + ((2 * c) ^ ((xl & 7) << 4));
    *(unsigned short*)(lds + boff) = f2bf(v);
  }
  __syncthreads();

  unsigned short* rowbase = t2 + (((size_t)b * H_ + y) * 130) * 128;
#pragma unroll
  for (int i = 0; i < 4; ++i) {
    const int xx = tid >> 2;
    const int cs = (tid & 3) + i * 4;   // 0..15
    short8 val = *(short8*)(lds + xx * 256 + ((cs * 16) ^ ((xx & 7) << 4)));
    *(short8*)(rowbase + (size_t)(x0 + xx + 1) * 128 + cs * 8) = val;
  }
  if (tid < 16) {
    short8 z = {0,0,0,0,0,0,0,0};
    if (xh == 0) *(short8*)(rowbase + tid * 8) = z;
    else         *(short8*)(rowbase + (size_t)129 * 128 + tid * 8) = z;
  }
}

// K2: fold affine chains; norms, logits, softmax -> WV, cst.
__global__ __launch_bounds__(256) void k_setup(const float* __restrict__ t,
    const float* __restrict__ w_r1, const float* __restrict__ b_r1,
    const float* __restrict__ w_r2, const float* __restrict__ b_r2,
    const float* __restrict__ w_r3, const float* __restrict__ b_r3,
    const float* __restrict__ w_t1, const float* __restrict__ b_t1,
    const float* __restrict__ w_t2, const float* __restrict__ b_t2,
    const float* __restrict__ w_t3, const float* __restrict__ b_t3,
    float* __restrict__ ws) {
  const int tid = threadIdx.x;
  __shared__ float aQ[256], bQ[256], aK[256], bK[256], aV[256], bV[256];

  if (tid < 128) {
    const int g = tid;
    float A1[4], B1[4], A2[2], B2[2];
#pragma unroll
    for (int j = 0; j < 4; ++j) { A1[j] = w_r1[g * 4 + j]; B1[j] = b_r1[g * 4 + j]; }
#pragma unroll
    for (int i = 0; i < 2; ++i) {
      A2[i] = 0.f; B2[i] = b_r2[g * 2 + i];
#pragma unroll
      for (int j = 0; j < 4; ++j) {
        const float w = w_r2[(g * 2 + i) * 4 + j];
        A2[i] = fmaf(w, A1[j], A2[i]); B2[i] = fmaf(w, B1[j], B2[i]);
      }
    }
#pragma unroll
    for (int o = 0; o < 2; ++o) {
      float a = 0.f, bb = b_r3[g * 2 + o];
#pragma unroll
      for (int i = 0; i < 2; ++i) {
        const float w = w_r3[(g * 2 + o) * 2 + i];
        a = fmaf(w, A2[i], a); bb = fmaf(w, B2[i], bb);
      }
      aQ[g * 2 + o] = a; bQ[g * 2 + o] = bb;
    }
#pragma unroll
    for (int j = 0; j < 4; ++j) { A1[j] = w_t1[g * 4 + j]; B1[j] = b_t1[g * 4 + j]; }
#pragma unroll
    for (int i = 0; i < 2; ++i) {
      A2[i] = 0.f; B2[i] = b_t2[g * 2 + i];
#pragma unroll
      for (int j = 0; j < 4; ++j) {
        const float w = w_t2[(g * 2 + i) * 4 + j];
        A2[i] = fmaf(w, A1[j], A2[i]); B2[i] = fmaf(w, B1[j], B2[i]);
      }
    }
#pragma unroll
    for (int o = 0; o < 4; ++o) {
      float a = 0.f, bb = b_t3[g * 4 + o];
#pragma unroll
      for (int i = 0; i < 2; ++i) {
        const float w = w_t3[(g * 4 + o) * 2 + i];
        a = fmaf(w, A2[i], a); bb = fmaf(w, B2[i], bb);
      }
      if (o < 2) { aK[g * 2 + o] = a; bK[g * 2 + o] = bb; }
      else       { aV[g * 2 + (o - 2)] = a; bV[g * 2 + (o - 2)] = bb; }
    }
  }
  __syncthreads();

  const float* M = ws + OFF_M;
  const float* S = ws + OFF_S;
  if (tid < 128) {
    const int b = tid >> 4, h = tid & 15, e = h >> 3, blk = h & 7, c0 = blk * 16;
    const float* Sx  = S;
    const float* Sxx = S + 1024;
    const float* Sto = S + 2048;
    const float* Stt = S + 3072;
    float rnq[16], rnk[16], gA[16], gB[16], kA[16], kB[16];
#pragma unroll
    for (int i = 0; i < 16; ++i) {
      const int g = c0 + i;
      const float a = aQ[g * 2 + e], bb = bQ[g * 2 + e];
      gA[i] = a; gB[i] = bb;
      float s2 = a * a * Sxx[b * C_ + g] + 2.f * a * bb * Sx[b * C_ + g] + bb * bb * 16384.f;
      rnq[i] = 1.f / fmaxf(sqrtf(fmaxf(s2, 0.f)), 1e-12f);
    }
#pragma unroll
    for (int j = 0; j < 16; ++j) {
      const int g = c0 + j;
      const float a = aK[g * 2 + e], bb = bK[g * 2 + e];
      kA[j] = a; kB[j] = bb;
      float s2 = a * a * Stt[b * C_ + g] + 2.f * a * bb * Sto[b * C_ + g] + bb * bb * 16384.f;
      rnk[j] = 1.f / fmaxf(sqrtf(fmaxf(s2, 0.f)), 1e-12f);
    }
    const float tt = t[h];
    const float* Mrow = M + (b * 8 + blk) * 256;
    float* WVp = ws + OFF_WV + (size_t)(b * 16 + h) * 256;
    float* cst = ws + OFF_CST + b * 256;
#pragma unroll
    for (int i = 0; i < 16; ++i) {
      float lg[16];
      float mx = -1e30f;
      const float sxi = Sx[b * C_ + c0 + i];
#pragma unroll
      for (int j = 0; j < 16; ++j) {
        const float s = gA[i] * kA[j] * Mrow[i * 16 + j]
                      + gA[i] * kB[j] * sxi
                      + gB[i] * kA[j] * Sto[b * C_ + c0 + j]
                      + gB[i] * kB[j] * 16384.f;
        const float l = tt * s * rnq[i] * rnk[j];
        lg[j] = l;
        mx = fmaxf(mx, l);
      }
      float den = 0.f;
#pragma unroll
      for (int j = 0; j < 16; ++j) { const float ev = expf(lg[j] - mx); lg[j] = ev; den += ev; }
      const float inv = 1.f / den;
      float cs = 0.f;
#pragma unroll
      for (int j = 0; j < 16; ++j) {
        const float aa = lg[j] * inv;
        const int gj = c0 + j;
        WVp[i * 16 + j] = aa * aV[gj * 2 + e];
        cs = fmaf(aa, bV[gj * 2 + e], cs);
      }
      cst[i * 16 + h] = cs;
    }
  }
}

// K3: fold attention into per-batch bf16 conv weights + constant taps.
__global__ __launch_bounds__(128) void k_weff(const float* __restrict__ w_f,
                                              float* __restrict__ ws) {
  const int b = blockIdx.x >> 7, oc = blockIdx.x & 127;
  const int c = threadIdx.x, blk = c >> 4, j = c & 15;
  const float* WVb = ws + OFF_WV;
  float acc[9];
#pragma unroll
  for (int k = 0; k < 9; ++k) acc[k] = 0.f;
#pragma unroll
  for (int e = 0; e < 2; ++e) {
    const int h = e * 8 + blk;
#pragma unroll
    for (int i = 0; i < 16; ++i) {
      const float coef = WVb[((size_t)(b * 16 + h) * 16 + i) * 16 + j];
      const float* wf = w_f + (size_t)(oc * 256 + i * 16 + h) * 9;
#pragma unroll
      for (int k = 0; k < 9; ++k) acc[k] = fmaf(wf[k], coef, acc[k]);
    }
  }
  unsigned short* wb16 = (unsigned short*)(ws + OFF_WEFF);
#pragma unroll
  for (int k = 0; k < 9; ++k)
    wb16[(((size_t)(b * 9 + k)) * 128 + oc) * 128 + c] = f2bf(acc[k]);

  __shared__ float tp[9][128];
  float tl[9];
#pragma unroll
  for (int k = 0; k < 9; ++k) tl[k] = 0.f;
  const float* cst = ws + OFF_CST + b * 256;
  for (int cc = c; cc < 256; cc += 128) {
    const float cv = cst[cc];
    const float* wf = w_f + (size_t)(oc * 256 + cc) * 9;
#pragma unroll
    for (int k = 0; k < 9; ++k) tl[k] = fmaf(wf[k], cv, tl[k]);
  }
#pragma unroll
  for (int k = 0; k < 9; ++k) tp[k][c] = tl[k];
  __syncthreads();
  for (int s = 64; s > 0; s >>= 1) {
    if (c < s) {
#pragma unroll
      for (int k = 0; k < 9; ++k) tp[k][c] += tp[k][c + s];
    }
    __syncthreads();
  }
  if (c < 9) ws[OFF_T + ((size_t)b * 128 + oc) * 9 + c] = tp[c][0];
}

// K4 fast: no-LDS-staging MFMA conv. Block (b,y) = 128oc x 128px, 4 waves of 64x64.
__global__ __launch_bounds__(256) void k_conv(const float* __restrict__ xin,
                                              const float* __restrict__ b_f,
                                              const float* __restrict__ ws,
                                              const unsigned short* __restrict__ t2,
                                              float* __restrict__ out) {
  const int d = blockIdx.x;
  const int b = d & 7;          // batch -> XCD
  const int y = d >> 3;
  const int tid = threadIdx.x;
  const int l = tid & 63, wv = tid >> 6;
  const int oc0 = (wv & 1) * 64, px0 = (wv >> 1) * 64;
  const int lm = l & 15, lh = l >> 4;

  f32x4 acc[4][4];
#pragma unroll
  for (int mt = 0; mt < 4; ++mt)
#pragma unroll
    for (int nt = 0; nt < 4; ++nt) acc[mt][nt] = (f32x4)0.f;

  const unsigned short* wA =
      (const unsigned short*)(ws + OFF_WEFF) + (size_t)b * 9 * 16384
      + (size_t)(oc0 + lm) * 128 + lh * 8;
  const unsigned short* t2b = t2 + ((size_t)b * H_) * 130 * 128
      + (size_t)(px0 + lm) * 128 + lh * 8;

#pragma unroll 1
  for (int dy = 0; dy < 3; ++dy) {
    const int yy = y + dy - 1;
    if ((unsigned)yy >= 128u) continue;
    const unsigned short* trow = t2b + (size_t)yy * 130 * 128;
#pragma unroll
    for (int dx = 0; dx < 3; ++dx) {
      const int tap = dy * 3 + dx;
      const unsigned short* wtap = wA + (size_t)tap * 16384;
      const unsigned short* tcol = trow + (size_t)dx * 128;
#pragma unroll
      for (int ks = 0; ks < 4; ++ks) {
        short8 bfr[4];
#pragma unroll
        for (int nt = 0; nt < 4; ++nt)
          bfr[nt] = *(const short8*)(tcol + (size_t)nt * 2048 + ks * 32);
#pragma unroll
        for (int mt = 0; mt < 4; ++mt) {
          const short8 af = *(const short8*)(wtap + (size_t)mt * 2048 + ks * 32);
          acc[mt][0] = mfma16(af, bfr[0], acc[mt][0]);
          acc[mt][1] = mfma16(af, bfr[1], acc[mt][1]);
          acc[mt][2] = mfma16(af, bfr[2], acc[mt][2]);
          acc[mt][3] = mfma16(af, bfr[3], acc[mt][3]);
        }
      }
    }
  }

  // epilogue
  __shared__ float sm[384];
  __syncthreads();
  if (tid < 128) {
    const float* Tk = ws + OFF_T + (size_t)(b * 128 + tid) * 9;
    float s = Tk[3] + Tk[4] + Tk[5], sl = Tk[3], sr = Tk[5];
    if (y >= 1)   { s += Tk[0] + Tk[1] + Tk[2]; sl += Tk[0]; sr += Tk[2]; }
    if (y <= 126) { s += Tk[6] + Tk[7] + Tk[8]; sl += Tk[6]; sr += Tk[8]; }
    sm[tid] = s + b_f[tid]; sm[128 + tid] = sl; sm[256 + tid] = sr;
  }
  __syncthreads();

#pragma unroll
  for (int mt = 0; mt < 4; ++mt)
#pragma unroll
    for (int nt = 0; nt < 4; ++nt) {
      const int px = px0 + nt * 16 + lm;
#pragma unroll
      for (int r = 0; r < 4; ++r) {
        const int oc = oc0 + mt * 16 + lh * 4 + r;
        float add = sm[oc];
        if (px == 0)   add -= sm[128 + oc];
        if (px == 127) add -= sm[256 + oc];
        const float z = acc[mt][nt][r] + add;
        const size_t base = ((size_t)(b * C_ + oc)) * HW_ + (size_t)y * W_ + px;
        const float rx = xin[base];
        out[base] = rx + (z >= 0.f ? z : 0.2f * z);
      }
    }
}

// K4 fallback (R2 version): used when ws_size can't hold T2.
__global__ __launch_bounds__(512, 4) void k_conv_fb(const float* __restrict__ xin,
                                                    const float* __restrict__ to,
                                                    const float* __restrict__ b_f,
                                                    const float* __restrict__ ws,
                                                    float* __restrict__ out) {
  const int bid = blockIdx.x;
  const int nb  = (bid & 7) * 128 + (bid >> 3);
  const int b   = nb >> 7;
  const int y   = nb & 127;
  const int tid = threadIdx.x;

  __shared__ f32x4 ldsbuf[3120];
  char* lp = (char*)ldsbuf;

  f32x4 acc[4][2];
#pragma unroll
  for (int mt = 0; mt < 4; ++mt)
#pragma unroll
    for (int nt = 0; nt < 2; ++nt) acc[mt][nt] = (f32x4)0.f;

  const float* tob = to + (size_t)b * C_ * HW_;
  const unsigned short* wb16 =
      (const unsigned short*)(ws + OFF_WEFF) + (size_t)b * 9 * 128 * 128;

  const int l = tid & 63, wv = tid >> 6;
  const int ocb0 = (wv & 1) * 64, pxb0 = (wv >> 1) * 32;
  const int lm = l & 15, lh = l >> 4;

  for (int cb = 0; cb < 128; cb += 64) {
    __syncthreads();
    {
      const int xg = tid & 31, cq = (tid >> 5) & 15;
      const int cbase = cb + cq * 4;
#pragma unroll
      for (int row = 0; row < 3; ++row) {
        const int y_in = y + row - 1;
        const bool yok = ((unsigned)y_in < 128u);
        const float* src = tob + (size_t)cbase * HW_ + (size_t)y_in * W_;
#pragma unroll
        for (int xb = 0; xb < 5; ++xb) {
          const int xi = xb * 32 + xg;
          if (xi < 130) {
            const int x_in = xi - 1;
            const bool ok = yok && ((unsigned)x_in < 128u);
            float f0 = 0.f, f1 = 0.f, f2 = 0.f, f3 = 0.f;
            if (ok) {
              f0 = src[x_in];
              f1 = src[HW_ + x_in];
              f2 = src[2 * HW_ + x_in];
              f3 = src[3 * HW_ + x_in];
            }
            ushort4 pk;
            pk.x = f2bf(f0); pk.y = f2bf(f1); pk.z = f2bf(f2); pk.w = f2bf(f3);
            const int boff = (row * 130 + xi) * 128 + ((cq * 8) ^ ((xi & 7) << 4));
            *(ushort4*)(lp + boff) = pk;
          }
        }
      }
    }
    __syncthreads();

    for (int tap = 0; tap < 9; ++tap) {
      const int dy = tap / 3, dx = tap - dy * 3;
#pragma unroll
      for (int ks = 0; ks < 2; ++ks) {
        short8 bfr[2];
#pragma unroll
        for (int nt = 0; nt < 2; ++nt) {
          const int xi = pxb0 + nt * 16 + lm + dx;
          const int boff = (dy * 130 + xi) * 128 + ((ks * 64 + lh * 16) ^ ((xi & 7) << 4));
          bfr[nt] = *(const short8*)(lp + boff);
        }
        const int cin = cb + ks * 32 + lh * 8;
#pragma unroll
        for (int mt = 0; mt < 4; ++mt) {
          const int oc = ocb0 + mt * 16 + lm;
          const short8 af = *(const short8*)(wb16 + ((size_t)tap * 128 + oc) * 128 + cin);
          acc[mt][0] = mfma16(af, bfr[0], acc[mt][0]);
          acc[mt][1] = mfma16(af, bfr[1], acc[mt][1]);
        }
      }
    }
  }

  __syncthreads();
  float* sAdd = (float*)ldsbuf;
  float* sLft = sAdd + 128;
  float* sRgt = sAdd + 256;
  if (tid < 128) {
    const float* Tk = ws + OFF_T + (size_t)(b * 128 + tid) * 9;
    float s = Tk[3] + Tk[4] + Tk[5], sl = Tk[3], sr = Tk[5];
    if (y >= 1)   { s += Tk[0] + Tk[1] + Tk[2]; sl += Tk[0]; sr += Tk[2]; }
    if (y <= 126) { s += Tk[6] + Tk[7] + Tk[8]; sl += Tk[6]; sr += Tk[8]; }
    sAdd[tid] = s + b_f[tid]; sLft[tid] = sl; sRgt[tid] = sr;
  }
  __syncthreads();

#pragma unroll
  for (int mt = 0; mt < 4; ++mt)
#pragma unroll
    for (int nt = 0; nt < 2; ++nt) {
      const int px = pxb0 + nt * 16 + lm;
#pragma unroll
      for (int r = 0; r < 4; ++r) {
        const int oc = ocb0 + mt * 16 + lh * 4 + r;
        float add = sAdd[oc];
        if (px == 0)   add -= sLft[oc];
        if (px == 127) add -= sRgt[oc];
        const float z = acc[mt][nt][r] + add;
        const size_t base = ((size_t)(b * C_ + oc)) * HW_ + (size_t)y * W_ + px;
        const float rx = xin[base];
        out[base] = rx + (z >= 0.f ? z : 0.2f * z);
      }
    }
}

extern "C" void kernel_launch(void* const* d_in, const int* in_sizes, int n_in,
                              void* d_out, int out_size, void* d_ws, size_t ws_size,
                              hipStream_t stream) {
  (void)in_sizes; (void)n_in; (void)out_size;
  const float* x    = (const float*)d_in[0];
  const float* to   = (const float*)d_in[1];
  const float* t    = (const float*)d_in[2];
  const float* w_r1 = (const float*)d_in[3];
  const float* b_r1 = (const float*)d_in[4];
  const float* w_r2 = (const float*)d_in[5];
  const float* b_r2 = (const float*)d_in[6];
  const float* w_r3 = (const float*)d_in[7];
  const float* b_r3 = (const float*)d_in[8];
  const float* w_t1 = (const float*)d_in[9];
  const float* b_t1 = (const float*)d_in[10];
  const float* w_t2 = (const float*)d_in[11];
  const float* b_t2 = (const float*)d_in[12];
  const float* w_t3 = (const float*)d_in[13];
  const float* b_t3 = (const float*)d_in[14];
  const float* w_f  = (const float*)d_in[15];
  const float* b_f  = (const float*)d_in[16];
  float* ws  = (float*)d_ws;
  float* out = (float*)d_out;
  unsigned short* t2 = (unsigned short*)(ws + OFF_T2F);
  const bool fast = (ws_size >= WS_NEED);

  k_reduce<<<1024, 256, 0, stream>>>(x, to, ws);
  k_redB<<<80, 256, 0, stream>>>(ws);
  if (fast) k_tr<<<2048, 256, 0, stream>>>(to, t2);
  k_setup<<<1, 256, 0, stream>>>(t, w_r1, b_r1, w_r2, b_r2, w_r3, b_r3,
                                 w_t1, b_t1, w_t2, b_t2, w_t3, b_t3, ws);
  k_weff<<<1024, 128, 0, stream>>>(w_f, ws);
  if (fast) k_conv<<<1024, 256, 0, stream>>>(x, b_f, ws, t2, out);
  else      k_conv_fb<<<1024, 512, 0, stream>>>(x, to, b_f, ws, out);
}

// Round 4
// 290.975 us; speedup vs baseline: 2.7997x; 1.3072x over previous
//
#include <hip/hip_runtime.h>
#include <math.h>

#define B_  8
#define C_  128
#define H_  128
#define W_  128
#define HW_ 16384

// ---- workspace layout (float offsets) ----
#define OFF_MPART 0          // [64 bblk][16 kc][256]     = 262144
#define OFF_SPART 262144     // [4 kind][1024 bc][16 kc]  = 65536
#define OFF_M     327680     // [64 bblk][256]            = 16384
#define OFF_S     344064     // [4 kind][1024 bc]         = 4096
#define OFF_WV    348160     // [8][16][16][16]           = 32768
#define OFF_CST   380928     // [8][256]                  = 2048
#define OFF_T     382976     // [8][128][9]               = 9216
#define OFF_WEFF  392192     // bf16 [8][9 tap][128 oc][128 cin] = 1179648 ushort = 589824 fl
#define OFF_T2F   982016     // bf16 T2 [8][128 y][130 x'][128 c] = 17039360 ushort
#define WS_NEED   (982016ull * 4ull + 34078720ull)

typedef __attribute__((ext_vector_type(8))) short short8;
typedef __attribute__((ext_vector_type(4))) float f32x4;

__device__ __forceinline__ unsigned short f2bf(float f) {
  unsigned u = __float_as_uint(f);
  u += 0x7fffu + ((u >> 16) & 1u);
  return (unsigned short)(u >> 16);
}

__device__ __forceinline__ f32x4 mfma16(short8 a, short8 b, f32x4 c) {
  return __builtin_amdgcn_mfma_f32_16x16x32_bf16(a, b, c, 0, 0, 0);
}

__device__ __forceinline__ float wave_sum64(float v) {
  v += __shfl_xor(v, 1);
  v += __shfl_xor(v, 2);
  v += __shfl_xor(v, 4);
  v += __shfl_xor(v, 8);
  v += __shfl_xor(v, 16);
  v += __shfl_xor(v, 32);
  return v;
}

// K1: per (b, blk, kc16): M_part[16][16] over 1024 px + per-channel partial moments.
__global__ __launch_bounds__(256) void k_reduce(const float* __restrict__ x,
                                                const float* __restrict__ to,
                                                float* __restrict__ ws) {
  const int bid  = blockIdx.x;            // 0..1023
  const int kc   = bid & 15;
  const int blk  = (bid >> 4) & 7;
  const int b    = bid >> 7;
  const int wave = threadIdx.x >> 6;
  const int lane = threadIdx.x & 63;
  const int c0   = blk * 16;
  const int i0   = wave * 4;

  const float* xb = x  + ((size_t)b * C_ + c0) * HW_;
  const float* tb = to + ((size_t)b * C_ + c0) * HW_;

  float acc[4][16];
#pragma unroll
  for (int a = 0; a < 4; ++a)
#pragma unroll
    for (int j = 0; j < 16; ++j) acc[a][j] = 0.f;
  float sx[4] = {0,0,0,0}, sxx[4] = {0,0,0,0}, st[4] = {0,0,0,0}, stt[4] = {0,0,0,0};

  const int pbase = kc * 1024 + lane;
#pragma unroll 1
  for (int it = 0; it < 16; ++it) {
    const int p = pbase + it * 64;
    float tv[16];
#pragma unroll
    for (int j = 0; j < 16; ++j) tv[j] = tb[j * HW_ + p];
    float xv[4];
#pragma unroll
    for (int a = 0; a < 4; ++a) xv[a] = xb[(i0 + a) * HW_ + p];
#pragma unroll
    for (int a = 0; a < 4; ++a)
#pragma unroll
      for (int j = 0; j < 16; ++j) acc[a][j] = fmaf(xv[a], tv[j], acc[a][j]);
#pragma unroll
    for (int a = 0; a < 4; ++a) { sx[a] += xv[a]; sxx[a] = fmaf(xv[a], xv[a], sxx[a]); }
#pragma unroll
    for (int j = 0; j < 16; ++j)
      if ((j >> 2) == wave) { st[j & 3] += tv[j]; stt[j & 3] = fmaf(tv[j], tv[j], stt[j & 3]); }
  }

#pragma unroll
  for (int a = 0; a < 4; ++a) {
#pragma unroll
    for (int j = 0; j < 16; ++j) acc[a][j] = wave_sum64(acc[a][j]);
    sx[a]  = wave_sum64(sx[a]);
    sxx[a] = wave_sum64(sxx[a]);
    st[a]  = wave_sum64(st[a]);
    stt[a] = wave_sum64(stt[a]);
  }

  if (lane == 0) {
    float* Mp = ws + OFF_MPART + (size_t)((b * 8 + blk) * 16 + kc) * 256;
#pragma unroll
    for (int a = 0; a < 4; ++a)
#pragma unroll
      for (int j = 0; j < 16; ++j) Mp[(i0 + a) * 16 + j] = acc[a][j];
    float* Sp = ws + OFF_SPART;
#pragma unroll
    for (int a = 0; a < 4; ++a) {
      const int cidx = b * C_ + c0 + i0 + a;
      Sp[0 * 16384 + cidx * 16 + kc] = sx[a];
      Sp[1 * 16384 + cidx * 16 + kc] = sxx[a];
      Sp[2 * 16384 + cidx * 16 + kc] = st[a];
      Sp[3 * 16384 + cidx * 16 + kc] = stt[a];
    }
  }
}

// K1b: parallel reduction of partials.
__global__ __launch_bounds__(256) void k_redB(float* __restrict__ ws) {
  const int gid = blockIdx.x * 256 + threadIdx.x;   // 80*256 = 20480
  if (gid < 16384) {
    const float* mp = ws + OFF_MPART + (size_t)(gid >> 8) * 4096 + (gid & 255);
    float s = 0.f;
#pragma unroll
    for (int kc = 0; kc < 16; ++kc) s += mp[kc * 256];
    ws[OFF_M + gid] = s;
  } else {
    const int sidx = gid - 16384;
    const float* sp = ws + OFF_SPART + (size_t)sidx * 16;
    float s = 0.f;
#pragma unroll
    for (int kc = 0; kc < 16; ++kc) s += sp[kc];
    ws[OFF_S + sidx] = s;
  }
}

// K_tr: transpose to -> bf16 T2[b][y][x'][c], x' = x+1, zero-padded x'=0/129.
__global__ __launch_bounds__(256) void k_tr(const float* __restrict__ to,
                                            unsigned short* __restrict__ t2) {
  const int d  = blockIdx.x;          // 2048 = xh(2) * y(128) * b(8)
  const int xh = d & 1;
  const int y  = (d >> 1) & 127;
  const int b  = d >> 8;
  const int tid = threadIdx.x;
  __shared__ char lds[64 * 256];      // 16 KB

  const int x0 = xh * 64;
  const int xl = tid & 63;
  const int cg = tid >> 6;            // 0..3
  const float* src = to + ((size_t)b * C_) * HW_ + (size_t)y * W_ + x0 + xl;
#pragma unroll
  for (int k = 0; k < 32; ++k) {
    const int c = cg * 32 + k;
    const float v = src[(size_t)c * HW_];
    const int boff = xl * 256 + ((2 * c) ^ ((xl & 7) << 4));
    *(unsigned short*)(lds + boff) = f2bf(v);
  }
  __syncthreads();

  unsigned short* rowbase = t2 + (((size_t)b * H_ + y) * 130) * 128;
#pragma unroll
  for (int i = 0; i < 4; ++i) {
    const int xx = tid >> 2;
    const int cs = (tid & 3) + i * 4;   // 0..15
    short8 val = *(short8*)(lds + xx * 256 + ((cs * 16) ^ ((xx & 7) << 4)));
    *(short8*)(rowbase + (size_t)(x0 + xx + 1) * 128 + cs * 8) = val;
  }
  if (tid < 16) {
    short8 z = {0,0,0,0,0,0,0,0};
    if (xh == 0) *(short8*)(rowbase + tid * 8) = z;
    else         *(short8*)(rowbase + (size_t)129 * 128 + tid * 8) = z;
  }
}

// K2: fold affine chains; norms, logits, softmax -> WV, cst.
__global__ __launch_bounds__(256) void k_setup(const float* __restrict__ t,
    const float* __restrict__ w_r1, const float* __restrict__ b_r1,
    const float* __restrict__ w_r2, const float* __restrict__ b_r2,
    const float* __restrict__ w_r3, const float* __restrict__ b_r3,
    const float* __restrict__ w_t1, const float* __restrict__ b_t1,
    const float* __restrict__ w_t2, const float* __restrict__ b_t2,
    const float* __restrict__ w_t3, const float* __restrict__ b_t3,
    float* __restrict__ ws) {
  const int tid = threadIdx.x;
  __shared__ float aQ[256], bQ[256], aK[256], bK[256], aV[256], bV[256];

  if (tid < 128) {
    const int g = tid;
    float A1[4], B1[4], A2[2], B2[2];
#pragma unroll
    for (int j = 0; j < 4; ++j) { A1[j] = w_r1[g * 4 + j]; B1[j] = b_r1[g * 4 + j]; }
#pragma unroll
    for (int i = 0; i < 2; ++i) {
      A2[i] = 0.f; B2[i] = b_r2[g * 2 + i];
#pragma unroll
      for (int j = 0; j < 4; ++j) {
        const float w = w_r2[(g * 2 + i) * 4 + j];
        A2[i] = fmaf(w, A1[j], A2[i]); B2[i] = fmaf(w, B1[j], B2[i]);
      }
    }
#pragma unroll
    for (int o = 0; o < 2; ++o) {
      float a = 0.f, bb = b_r3[g * 2 + o];
#pragma unroll
      for (int i = 0; i < 2; ++i) {
        const float w = w_r3[(g * 2 + o) * 2 + i];
        a = fmaf(w, A2[i], a); bb = fmaf(w, B2[i], bb);
      }
      aQ[g * 2 + o] = a; bQ[g * 2 + o] = bb;
    }
#pragma unroll
    for (int j = 0; j < 4; ++j) { A1[j] = w_t1[g * 4 + j]; B1[j] = b_t1[g * 4 + j]; }
#pragma unroll
    for (int i = 0; i < 2; ++i) {
      A2[i] = 0.f; B2[i] = b_t2[g * 2 + i];
#pragma unroll
      for (int j = 0; j < 4; ++j) {
        const float w = w_t2[(g * 2 + i) * 4 + j];
        A2[i] = fmaf(w, A1[j], A2[i]); B2[i] = fmaf(w, B1[j], B2[i]);
      }
    }
#pragma unroll
    for (int o = 0; o < 4; ++o) {
      float a = 0.f, bb = b_t3[g * 4 + o];
#pragma unroll
      for (int i = 0; i < 2; ++i) {
        const float w = w_t3[(g * 4 + o) * 2 + i];
        a = fmaf(w, A2[i], a); bb = fmaf(w, B2[i], bb);
      }
      if (o < 2) { aK[g * 2 + o] = a; bK[g * 2 + o] = bb; }
      else       { aV[g * 2 + (o - 2)] = a; bV[g * 2 + (o - 2)] = bb; }
    }
  }
  __syncthreads();

  const float* M = ws + OFF_M;
  const float* S = ws + OFF_S;
  if (tid < 128) {
    const int b = tid >> 4, h = tid & 15, e = h >> 3, blk = h & 7, c0 = blk * 16;
    const float* Sx  = S;
    const float* Sxx = S + 1024;
    const float* Sto = S + 2048;
    const float* Stt = S + 3072;
    float rnq[16], rnk[16], gA[16], gB[16], kA[16], kB[16];
#pragma unroll
    for (int i = 0; i < 16; ++i) {
      const int g = c0 + i;
      const float a = aQ[g * 2 + e], bb = bQ[g * 2 + e];
      gA[i] = a; gB[i] = bb;
      float s2 = a * a * Sxx[b * C_ + g] + 2.f * a * bb * Sx[b * C_ + g] + bb * bb * 16384.f;
      rnq[i] = 1.f / fmaxf(sqrtf(fmaxf(s2, 0.f)), 1e-12f);
    }
#pragma unroll
    for (int j = 0; j < 16; ++j) {
      const int g = c0 + j;
      const float a = aK[g * 2 + e], bb = bK[g * 2 + e];
      kA[j] = a; kB[j] = bb;
      float s2 = a * a * Stt[b * C_ + g] + 2.f * a * bb * Sto[b * C_ + g] + bb * bb * 16384.f;
      rnk[j] = 1.f / fmaxf(sqrtf(fmaxf(s2, 0.f)), 1e-12f);
    }
    const float tt = t[h];
    const float* Mrow = M + (b * 8 + blk) * 256;
    float* WVp = ws + OFF_WV + (size_t)(b * 16 + h) * 256;
    float* cst = ws + OFF_CST + b * 256;
#pragma unroll
    for (int i = 0; i < 16; ++i) {
      float lg[16];
      float mx = -1e30f;
      const float sxi = Sx[b * C_ + c0 + i];
#pragma unroll
      for (int j = 0; j < 16; ++j) {
        const float s = gA[i] * kA[j] * Mrow[i * 16 + j]
                      + gA[i] * kB[j] * sxi
                      + gB[i] * kA[j] * Sto[b * C_ + c0 + j]
                      + gB[i] * kB[j] * 16384.f;
        const float l = tt * s * rnq[i] * rnk[j];
        lg[j] = l;
        mx = fmaxf(mx, l);
      }
      float den = 0.f;
#pragma unroll
      for (int j = 0; j < 16; ++j) { const float ev = expf(lg[j] - mx); lg[j] = ev; den += ev; }
      const float inv = 1.f / den;
      float cs = 0.f;
#pragma unroll
      for (int j = 0; j < 16; ++j) {
        const float aa = lg[j] * inv;
        const int gj = c0 + j;
        WVp[i * 16 + j] = aa * aV[gj * 2 + e];
        cs = fmaf(aa, bV[gj * 2 + e], cs);
      }
      cst[i * 16 + h] = cs;
    }
  }
}

// K3: fold attention into per-batch bf16 conv weights + constant taps.
__global__ __launch_bounds__(128) void k_weff(const float* __restrict__ w_f,
                                              float* __restrict__ ws) {
  const int b = blockIdx.x >> 7, oc = blockIdx.x & 127;
  const int c = threadIdx.x, blk = c >> 4, j = c & 15;
  const float* WVb = ws + OFF_WV;
  float acc[9];
#pragma unroll
  for (int k = 0; k < 9; ++k) acc[k] = 0.f;
#pragma unroll
  for (int e = 0; e < 2; ++e) {
    const int h = e * 8 + blk;
#pragma unroll
    for (int i = 0; i < 16; ++i) {
      const float coef = WVb[((size_t)(b * 16 + h) * 16 + i) * 16 + j];
      const float* wf = w_f + (size_t)(oc * 256 + i * 16 + h) * 9;
#pragma unroll
      for (int k = 0; k < 9; ++k) acc[k] = fmaf(wf[k], coef, acc[k]);
    }
  }
  unsigned short* wb16 = (unsigned short*)(ws + OFF_WEFF);
#pragma unroll
  for (int k = 0; k < 9; ++k)
    wb16[(((size_t)(b * 9 + k)) * 128 + oc) * 128 + c] = f2bf(acc[k]);

  __shared__ float tp[9][128];
  float tl[9];
#pragma unroll
  for (int k = 0; k < 9; ++k) tl[k] = 0.f;
  const float* cst = ws + OFF_CST + b * 256;
  for (int cc = c; cc < 256; cc += 128) {
    const float cv = cst[cc];
    const float* wf = w_f + (size_t)(oc * 256 + cc) * 9;
#pragma unroll
    for (int k = 0; k < 9; ++k) tl[k] = fmaf(wf[k], cv, tl[k]);
  }
#pragma unroll
  for (int k = 0; k < 9; ++k) tp[k][c] = tl[k];
  __syncthreads();
  for (int s = 64; s > 0; s >>= 1) {
    if (c < s) {
#pragma unroll
      for (int k = 0; k < 9; ++k) tp[k][c] += tp[k][c + s];
    }
    __syncthreads();
  }
  if (c < 9) ws[OFF_T + ((size_t)b * 128 + oc) * 9 + c] = tp[c][0];
}

// K4: weight-stationary MFMA conv. Block = (b, oc-half 64, y-pair).
// A (9 taps x 64 oc x 128 cin bf16 = 144 KiB) staged once in LDS, XOR-swizzled.
// 8 waves: wave w -> row (w&1), px-quarter (w>>2? no: w>>1)*32. B streamed from T2 (L2).
__global__ __launch_bounds__(512, 2) void k_conv(const float* __restrict__ xin,
                                                 const float* __restrict__ b_f,
                                                 const float* __restrict__ ws,
                                                 const unsigned short* __restrict__ t2,
                                                 float* __restrict__ out) {
  const int d = blockIdx.x;           // 1024 = 8 b * 2 half * 64 ypair
  const int b    = d & 7;             // batch -> XCD
  const int half = (d >> 3) & 1;
  const int y0   = (d >> 4) * 2;
  const int tid  = threadIdx.x;
  const int oc0h = half * 64;

  __shared__ short8 A_s[9216];        // 147456 B = 144 KiB

  // stage A: [tap][64 oc][128 cin] bf16, byte ^= ((oc&15)<<4) within each 256B row
  {
    const unsigned short* wsrc = (const unsigned short*)(ws + OFF_WEFF)
        + (size_t)b * 9 * 16384 + (size_t)oc0h * 128;
#pragma unroll
    for (int ii = 0; ii < 18; ++ii) {
      const int idx = ii * 512 + tid;
      const int ch = idx & 15, oc = (idx >> 4) & 63, tap = idx >> 10;
      const short8 v = *(const short8*)(wsrc + ((size_t)tap * 128 + oc) * 128 + ch * 8);
      const int dstb = (tap * 64 + oc) * 256 + ((ch ^ (oc & 15)) << 4);
      *(short8*)((char*)A_s + dstb) = v;
    }
  }
  __syncthreads();

  const int l = tid & 63, w = tid >> 6;
  const int row = w & 1, pxq = w >> 1;
  const int y = y0 + row, px0 = pxq * 32;
  const int lm = l & 15, lh = l >> 4;

  f32x4 acc[4][2];
#pragma unroll
  for (int mt = 0; mt < 4; ++mt) { acc[mt][0] = (f32x4)0.f; acc[mt][1] = (f32x4)0.f; }

  const unsigned short* t2b = t2 + ((size_t)b * H_) * 130 * 128
      + (size_t)(px0 + lm) * 128 + lh * 8;

#pragma unroll
  for (int dy = 0; dy < 3; ++dy) {
    const int yy = y + dy - 1;
    if ((unsigned)yy < 128u) {
      const unsigned short* trow = t2b + (size_t)yy * (130 * 128);
#pragma unroll
      for (int dx = 0; dx < 3; ++dx) {
        const int tap = dy * 3 + dx;
        const unsigned short* tcol = trow + (size_t)dx * 128;
#pragma unroll
        for (int ks = 0; ks < 4; ++ks) {
          const short8 b0 = *(const short8*)(tcol + ks * 32);
          const short8 b1 = *(const short8*)(tcol + 2048 + ks * 32);
#pragma unroll
          for (int mt = 0; mt < 4; ++mt) {
            const int ocl = mt * 16 + lm;
            const int abyte = (tap * 64 + ocl) * 256 + ((((4 * ks + lh) ^ (ocl & 15))) << 4);
            const short8 af = *(const short8*)((const char*)A_s + abyte);
            acc[mt][0] = mfma16(af, b0, acc[mt][0]);
            acc[mt][1] = mfma16(af, b1, acc[mt][1]);
          }
        }
      }
    }
  }

  // epilogue: per (row, oc) constant terms into LDS (reuses A_s region)
  __syncthreads();
  float* sm = (float*)A_s;   // [2][384]: add, left, right
  if (tid < 256) {
    const int rr = tid >> 7, oc = tid & 127;
    const int yv = y0 + rr;
    const float* Tk = ws + OFF_T + (size_t)(b * 128 + oc) * 9;
    float s = Tk[3] + Tk[4] + Tk[5], sl = Tk[3], sr = Tk[5];
    if (yv >= 1)   { s += Tk[0] + Tk[1] + Tk[2]; sl += Tk[0]; sr += Tk[2]; }
    if (yv <= 126) { s += Tk[6] + Tk[7] + Tk[8]; sl += Tk[6]; sr += Tk[8]; }
    sm[rr * 384 + oc] = s + b_f[oc];
    sm[rr * 384 + 128 + oc] = sl;
    sm[rr * 384 + 256 + oc] = sr;
  }
  __syncthreads();

#pragma unroll
  for (int mt = 0; mt < 4; ++mt)
#pragma unroll
    for (int nt = 0; nt < 2; ++nt) {
      const int px = px0 + nt * 16 + lm;
#pragma unroll
      for (int r = 0; r < 4; ++r) {
        const int oc = oc0h + mt * 16 + lh * 4 + r;
        float add = sm[row * 384 + oc];
        if (px == 0)   add -= sm[row * 384 + 128 + oc];
        if (px == 127) add -= sm[row * 384 + 256 + oc];
        const float z = acc[mt][nt][r] + add;
        const size_t base = ((size_t)(b * C_ + oc)) * HW_ + (size_t)y * W_ + px;
        const float rx = xin[base];
        out[base] = rx + (z >= 0.f ? z : 0.2f * z);
      }
    }
}

// K4 fallback (R2 version): used when ws_size can't hold T2.
__global__ __launch_bounds__(512, 4) void k_conv_fb(const float* __restrict__ xin,
                                                    const float* __restrict__ to,
                                                    const float* __restrict__ b_f,
                                                    const float* __restrict__ ws,
                                                    float* __restrict__ out) {
  const int bid = blockIdx.x;
  const int nb  = (bid & 7) * 128 + (bid >> 3);
  const int b   = nb >> 7;
  const int y   = nb & 127;
  const int tid = threadIdx.x;

  __shared__ f32x4 ldsbuf[3120];
  char* lp = (char*)ldsbuf;

  f32x4 acc[4][2];
#pragma unroll
  for (int mt = 0; mt < 4; ++mt)
#pragma unroll
    for (int nt = 0; nt < 2; ++nt) acc[mt][nt] = (f32x4)0.f;

  const float* tob = to + (size_t)b * C_ * HW_;
  const unsigned short* wb16 =
      (const unsigned short*)(ws + OFF_WEFF) + (size_t)b * 9 * 128 * 128;

  const int l = tid & 63, wv = tid >> 6;
  const int ocb0 = (wv & 1) * 64, pxb0 = (wv >> 1) * 32;
  const int lm = l & 15, lh = l >> 4;

  for (int cb = 0; cb < 128; cb += 64) {
    __syncthreads();
    {
      const int xg = tid & 31, cq = (tid >> 5) & 15;
      const int cbase = cb + cq * 4;
#pragma unroll
      for (int row = 0; row < 3; ++row) {
        const int y_in = y + row - 1;
        const bool yok = ((unsigned)y_in < 128u);
        const float* src = tob + (size_t)cbase * HW_ + (size_t)y_in * W_;
#pragma unroll
        for (int xb = 0; xb < 5; ++xb) {
          const int xi = xb * 32 + xg;
          if (xi < 130) {
            const int x_in = xi - 1;
            const bool ok = yok && ((unsigned)x_in < 128u);
            float f0 = 0.f, f1 = 0.f, f2 = 0.f, f3 = 0.f;
            if (ok) {
              f0 = src[x_in];
              f1 = src[HW_ + x_in];
              f2 = src[2 * HW_ + x_in];
              f3 = src[3 * HW_ + x_in];
            }
            ushort4 pk;
            pk.x = f2bf(f0); pk.y = f2bf(f1); pk.z = f2bf(f2); pk.w = f2bf(f3);
            const int boff = (row * 130 + xi) * 128 + ((cq * 8) ^ ((xi & 7) << 4));
            *(ushort4*)(lp + boff) = pk;
          }
        }
      }
    }
    __syncthreads();

    for (int tap = 0; tap < 9; ++tap) {
      const int dy = tap / 3, dx = tap - dy * 3;
#pragma unroll
      for (int ks = 0; ks < 2; ++ks) {
        short8 bfr[2];
#pragma unroll
        for (int nt = 0; nt < 2; ++nt) {
          const int xi = pxb0 + nt * 16 + lm + dx;
          const int boff = (dy * 130 + xi) * 128 + ((ks * 64 + lh * 16) ^ ((xi & 7) << 4));
          bfr[nt] = *(const short8*)(lp + boff);
        }
        const int cin = cb + ks * 32 + lh * 8;
#pragma unroll
        for (int mt = 0; mt < 4; ++mt) {
          const int oc = ocb0 + mt * 16 + lm;
          const short8 af = *(const short8*)(wb16 + ((size_t)tap * 128 + oc) * 128 + cin);
          acc[mt][0] = mfma16(af, bfr[0], acc[mt][0]);
          acc[mt][1] = mfma16(af, bfr[1], acc[mt][1]);
        }
      }
    }
  }

  __syncthreads();
  float* sAdd = (float*)ldsbuf;
  float* sLft = sAdd + 128;
  float* sRgt = sAdd + 256;
  if (tid < 128) {
    const float* Tk = ws + OFF_T + (size_t)(b * 128 + tid) * 9;
    float s = Tk[3] + Tk[4] + Tk[5], sl = Tk[3], sr = Tk[5];
    if (y >= 1)   { s += Tk[0] + Tk[1] + Tk[2]; sl += Tk[0]; sr += Tk[2]; }
    if (y <= 126) { s += Tk[6] + Tk[7] + Tk[8]; sl += Tk[6]; sr += Tk[8]; }
    sAdd[tid] = s + b_f[tid]; sLft[tid] = sl; sRgt[tid] = sr;
  }
  __syncthreads();

#pragma unroll
  for (int mt = 0; mt < 4; ++mt)
#pragma unroll
    for (int nt = 0; nt < 2; ++nt) {
      const int px = pxb0 + nt * 16 + lm;
#pragma unroll
      for (int r = 0; r < 4; ++r) {
        const int oc = ocb0 + mt * 16 + lh * 4 + r;
        float add = sAdd[oc];
        if (px == 0)   add -= sLft[oc];
        if (px == 127) add -= sRgt[oc];
        const float z = acc[mt][nt][r] + add;
        const size_t base = ((size_t)(b * C_ + oc)) * HW_ + (size_t)y * W_ + px;
        const float rx = xin[base];
        out[base] = rx + (z >= 0.f ? z : 0.2f * z);
      }
    }
}

extern "C" void kernel_launch(void* const* d_in, const int* in_sizes, int n_in,
                              void* d_out, int out_size, void* d_ws, size_t ws_size,
                              hipStream_t stream) {
  (void)in_sizes; (void)n_in; (void)out_size;
  const float* x    = (const float*)d_in[0];
  const float* to   = (const float*)d_in[1];
  const float* t    = (const float*)d_in[2];
  const float* w_r1 = (const float*)d_in[3];
  const float* b_r1 = (const float*)d_in[4];
  const float* w_r2 = (const float*)d_in[5];
  const float* b_r2 = (const float*)d_in[6];
  const float* w_r3 = (const float*)d_in[7];
  const float* b_r3 = (const float*)d_in[8];
  const float* w_t1 = (const float*)d_in[9];
  const float* b_t1 = (const float*)d_in[10];
  const float* w_t2 = (const float*)d_in[11];
  const float* b_t2 = (const float*)d_in[12];
  const float* w_t3 = (const float*)d_in[13];
  const float* b_t3 = (const float*)d_in[14];
  const float* w_f  = (const float*)d_in[15];
  const float* b_f  = (const float*)d_in[16];
  float* ws  = (float*)d_ws;
  float* out = (float*)d_out;
  unsigned short* t2 = (unsigned short*)(ws + OFF_T2F);
  const bool fast = (ws_size >= WS_NEED);

  k_reduce<<<1024, 256, 0, stream>>>(x, to, ws);
  k_redB<<<80, 256, 0, stream>>>(ws);
  if (fast) k_tr<<<2048, 256, 0, stream>>>(to, t2);
  k_setup<<<1, 256, 0, stream>>>(t, w_r1, b_r1, w_r2, b_r2, w_r3, b_r3,
                                 w_t1, b_t1, w_t2, b_t2, w_t3, b_t3, ws);
  k_weff<<<1024, 128, 0, stream>>>(w_f, ws);
  if (fast) k_conv<<<1024, 512, 0, stream>>>(x, b_f, ws, t2, out);
  else      k_conv_fb<<<1024, 512, 0, stream>>>(x, to, b_f, ws, out);
}

// Round 5
// 178.591 us; speedup vs baseline: 4.5615x; 1.6293x over previous
//
#include <hip/hip_runtime.h>
#include <math.h>

#define B_  8
#define C_  128
#define H_  128
#define W_  128
#define HW_ 16384

// ---- workspace layout (float offsets) ----
#define OFF_MPART 0          // [64 bblk][16 kc][256]     = 262144
#define OFF_SPART 262144     // [4 kind][1024 bc][16 kc]  = 65536
#define OFF_M     327680     // [64 bblk][256]            = 16384
#define OFF_S     344064     // [4 kind][1024 bc]         = 4096
#define OFF_WV    348160     // [8][16][16][16]           = 32768
#define OFF_CST   380928     // [8][256]                  = 2048
#define OFF_T     382976     // [8][128][9]               = 9216
#define OFF_WEFF  392192     // bf16 [8][9 tap][128 oc][128 cin] = 1179648 ushort = 589824 fl
#define OFF_T2F   982016     // bf16 T2 [8][128 y][130 x'][128 c] = 17039360 ushort
#define WS_NEED   (982016ull * 4ull + 34078720ull)

typedef __attribute__((ext_vector_type(8))) short short8;
typedef __attribute__((ext_vector_type(4))) float f32x4;

__device__ __forceinline__ unsigned short f2bf(float f) {
  unsigned u = __float_as_uint(f);
  u += 0x7fffu + ((u >> 16) & 1u);
  return (unsigned short)(u >> 16);
}

__device__ __forceinline__ f32x4 mfma16(short8 a, short8 b, f32x4 c) {
  return __builtin_amdgcn_mfma_f32_16x16x32_bf16(a, b, c, 0, 0, 0);
}

__device__ __forceinline__ float wave_sum64(float v) {
  v += __shfl_xor(v, 1);
  v += __shfl_xor(v, 2);
  v += __shfl_xor(v, 4);
  v += __shfl_xor(v, 8);
  v += __shfl_xor(v, 16);
  v += __shfl_xor(v, 32);
  return v;
}

// K1: per (b, blk, kc16): M_part[16][16] over 1024 px + per-channel partial moments.
__global__ __launch_bounds__(256) void k_reduce(const float* __restrict__ x,
                                                const float* __restrict__ to,
                                                float* __restrict__ ws) {
  const int bid  = blockIdx.x;            // 0..1023
  const int kc   = bid & 15;
  const int blk  = (bid >> 4) & 7;
  const int b    = bid >> 7;
  const int wave = threadIdx.x >> 6;
  const int lane = threadIdx.x & 63;
  const int c0   = blk * 16;
  const int i0   = wave * 4;

  const float* xb = x  + ((size_t)b * C_ + c0) * HW_;
  const float* tb = to + ((size_t)b * C_ + c0) * HW_;

  float acc[4][16];
#pragma unroll
  for (int a = 0; a < 4; ++a)
#pragma unroll
    for (int j = 0; j < 16; ++j) acc[a][j] = 0.f;
  float sx[4] = {0,0,0,0}, sxx[4] = {0,0,0,0}, st[4] = {0,0,0,0}, stt[4] = {0,0,0,0};

  const int pbase = kc * 1024 + lane;
#pragma unroll 1
  for (int it = 0; it < 16; ++it) {
    const int p = pbase + it * 64;
    float tv[16];
#pragma unroll
    for (int j = 0; j < 16; ++j) tv[j] = tb[j * HW_ + p];
    float xv[4];
#pragma unroll
    for (int a = 0; a < 4; ++a) xv[a] = xb[(i0 + a) * HW_ + p];
#pragma unroll
    for (int a = 0; a < 4; ++a)
#pragma unroll
      for (int j = 0; j < 16; ++j) acc[a][j] = fmaf(xv[a], tv[j], acc[a][j]);
#pragma unroll
    for (int a = 0; a < 4; ++a) { sx[a] += xv[a]; sxx[a] = fmaf(xv[a], xv[a], sxx[a]); }
#pragma unroll
    for (int j = 0; j < 16; ++j)
      if ((j >> 2) == wave) { st[j & 3] += tv[j]; stt[j & 3] = fmaf(tv[j], tv[j], stt[j & 3]); }
  }

#pragma unroll
  for (int a = 0; a < 4; ++a) {
#pragma unroll
    for (int j = 0; j < 16; ++j) acc[a][j] = wave_sum64(acc[a][j]);
    sx[a]  = wave_sum64(sx[a]);
    sxx[a] = wave_sum64(sxx[a]);
    st[a]  = wave_sum64(st[a]);
    stt[a] = wave_sum64(stt[a]);
  }

  if (lane == 0) {
    float* Mp = ws + OFF_MPART + (size_t)((b * 8 + blk) * 16 + kc) * 256;
#pragma unroll
    for (int a = 0; a < 4; ++a)
#pragma unroll
      for (int j = 0; j < 16; ++j) Mp[(i0 + a) * 16 + j] = acc[a][j];
    float* Sp = ws + OFF_SPART;
#pragma unroll
    for (int a = 0; a < 4; ++a) {
      const int cidx = b * C_ + c0 + i0 + a;
      Sp[0 * 16384 + cidx * 16 + kc] = sx[a];
      Sp[1 * 16384 + cidx * 16 + kc] = sxx[a];
      Sp[2 * 16384 + cidx * 16 + kc] = st[a];
      Sp[3 * 16384 + cidx * 16 + kc] = stt[a];
    }
  }
}

// K1b: parallel reduction of partials.
__global__ __launch_bounds__(256) void k_redB(float* __restrict__ ws) {
  const int gid = blockIdx.x * 256 + threadIdx.x;   // 80*256 = 20480
  if (gid < 16384) {
    const float* mp = ws + OFF_MPART + (size_t)(gid >> 8) * 4096 + (gid & 255);
    float s = 0.f;
#pragma unroll
    for (int kc = 0; kc < 16; ++kc) s += mp[kc * 256];
    ws[OFF_M + gid] = s;
  } else {
    const int sidx = gid - 16384;
    const float* sp = ws + OFF_SPART + (size_t)sidx * 16;
    float s = 0.f;
#pragma unroll
    for (int kc = 0; kc < 16; ++kc) s += sp[kc];
    ws[OFF_S + sidx] = s;
  }
}

// K_tr: transpose to -> bf16 T2[b][y][x'][c], x' = x+1, zero-padded x'=0/129.
__global__ __launch_bounds__(256) void k_tr(const float* __restrict__ to,
                                            unsigned short* __restrict__ t2) {
  const int d  = blockIdx.x;          // 2048 = xh(2) * y(128) * b(8)
  const int xh = d & 1;
  const int y  = (d >> 1) & 127;
  const int b  = d >> 8;
  const int tid = threadIdx.x;
  __shared__ char lds[64 * 256];      // 16 KB

  const int x0 = xh * 64;
  const int xl = tid & 63;
  const int cg = tid >> 6;            // 0..3
  const float* src = to + ((size_t)b * C_) * HW_ + (size_t)y * W_ + x0 + xl;
#pragma unroll
  for (int k = 0; k < 32; ++k) {
    const int c = cg * 32 + k;
    const float v = src[(size_t)c * HW_];
    const int boff = xl * 256 + ((2 * c) ^ ((xl & 7) << 4));
    *(unsigned short*)(lds + boff) = f2bf(v);
  }
  __syncthreads();

  unsigned short* rowbase = t2 + (((size_t)b * H_ + y) * 130) * 128;
#pragma unroll
  for (int i = 0; i < 4; ++i) {
    const int xx = tid >> 2;
    const int cs = (tid & 3) + i * 4;   // 0..15
    short8 val = *(short8*)(lds + xx * 256 + ((cs * 16) ^ ((xx & 7) << 4)));
    *(short8*)(rowbase + (size_t)(x0 + xx + 1) * 128 + cs * 8) = val;
  }
  if (tid < 16) {
    short8 z = {0,0,0,0,0,0,0,0};
    if (xh == 0) *(short8*)(rowbase + tid * 8) = z;
    else         *(short8*)(rowbase + (size_t)129 * 128 + tid * 8) = z;
  }
}

// K2 (parallel): one block per batch, thread = (h, i). Fold affine chains into
// LDS, per-(h,j) K-norm coefs into LDS, then logits+softmax -> WV, cst.
__global__ __launch_bounds__(256) void k_attn(const float* __restrict__ t,
    const float* __restrict__ w_r1, const float* __restrict__ b_r1,
    const float* __restrict__ w_r2, const float* __restrict__ b_r2,
    const float* __restrict__ w_r3, const float* __restrict__ b_r3,
    const float* __restrict__ w_t1, const float* __restrict__ b_t1,
    const float* __restrict__ w_t2, const float* __restrict__ b_t2,
    const float* __restrict__ w_t3, const float* __restrict__ b_t3,
    float* __restrict__ ws) {
  const int b = blockIdx.x;          // 0..7
  const int tid = threadIdx.x;       // h = tid>>4, i = tid&15
  __shared__ float aQ[256], bQ[256], aK[256], bK[256], aV[256], bV[256];
  __shared__ float rks[256], kAs[256], kBs[256], stos[256];

  // Phase A: coefficient folding (identical math to R4 k_setup)
  if (tid < 128) {
    const int g = tid;
    float A1[4], B1[4], A2[2], B2[2];
#pragma unroll
    for (int j = 0; j < 4; ++j) { A1[j] = w_r1[g * 4 + j]; B1[j] = b_r1[g * 4 + j]; }
#pragma unroll
    for (int i = 0; i < 2; ++i) {
      A2[i] = 0.f; B2[i] = b_r2[g * 2 + i];
#pragma unroll
      for (int j = 0; j < 4; ++j) {
        const float w = w_r2[(g * 2 + i) * 4 + j];
        A2[i] = fmaf(w, A1[j], A2[i]); B2[i] = fmaf(w, B1[j], B2[i]);
      }
    }
#pragma unroll
    for (int o = 0; o < 2; ++o) {
      float a = 0.f, bb = b_r3[g * 2 + o];
#pragma unroll
      for (int i = 0; i < 2; ++i) {
        const float w = w_r3[(g * 2 + o) * 2 + i];
        a = fmaf(w, A2[i], a); bb = fmaf(w, B2[i], bb);
      }
      aQ[g * 2 + o] = a; bQ[g * 2 + o] = bb;
    }
#pragma unroll
    for (int j = 0; j < 4; ++j) { A1[j] = w_t1[g * 4 + j]; B1[j] = b_t1[g * 4 + j]; }
#pragma unroll
    for (int i = 0; i < 2; ++i) {
      A2[i] = 0.f; B2[i] = b_t2[g * 2 + i];
#pragma unroll
      for (int j = 0; j < 4; ++j) {
        const float w = w_t2[(g * 2 + i) * 4 + j];
        A2[i] = fmaf(w, A1[j], A2[i]); B2[i] = fmaf(w, B1[j], B2[i]);
      }
    }
#pragma unroll
    for (int o = 0; o < 4; ++o) {
      float a = 0.f, bb = b_t3[g * 4 + o];
#pragma unroll
      for (int i = 0; i < 2; ++i) {
        const float w = w_t3[(g * 4 + o) * 2 + i];
        a = fmaf(w, A2[i], a); bb = fmaf(w, B2[i], bb);
      }
      if (o < 2) { aK[g * 2 + o] = a; bK[g * 2 + o] = bb; }
      else       { aV[g * 2 + (o - 2)] = a; bV[g * 2 + (o - 2)] = bb; }
    }
  }
  __syncthreads();

  const float* S   = ws + OFF_S;
  const float* Sx  = S;
  const float* Sxx = S + 1024;
  const float* Sto = S + 2048;
  const float* Stt = S + 3072;

  // Phase B: per-(h, j=tid&15) K-side norm + coefs into LDS
  {
    const int h = tid >> 4, e = h >> 3, blk = h & 7, c0 = blk * 16;
    const int g = c0 + (tid & 15);
    const float a = aK[g * 2 + e], bb = bK[g * 2 + e];
    const float s2 = a * a * Stt[b * C_ + g] + 2.f * a * bb * Sto[b * C_ + g]
                   + bb * bb * 16384.f;
    rks[tid] = 1.f / fmaxf(sqrtf(fmaxf(s2, 0.f)), 1e-12f);
    kAs[tid] = a; kBs[tid] = bb;
    stos[tid] = Sto[b * C_ + g];
  }
  __syncthreads();

  // Phase C: thread = (h, i): 16 logits, softmax, WV row + cst entry
  {
    const int h = tid >> 4, i = tid & 15, e = h >> 3, blk = h & 7, c0 = blk * 16;
    const int gi = c0 + i;
    const float gA = aQ[gi * 2 + e], gB = bQ[gi * 2 + e];
    const float sxi = Sx[b * C_ + gi];
    const float q2 = gA * gA * Sxx[b * C_ + gi] + 2.f * gA * gB * sxi
                   + gB * gB * 16384.f;
    const float rnq = 1.f / fmaxf(sqrtf(fmaxf(q2, 0.f)), 1e-12f);
    const float tt = t[h];
    const float* Mrow = ws + OFF_M + (size_t)(b * 8 + blk) * 256 + i * 16;

    float lg[16];
    float mx = -1e30f;
#pragma unroll
    for (int j = 0; j < 16; ++j) {
      const float s = gA * kAs[h * 16 + j] * Mrow[j]
                    + gA * kBs[h * 16 + j] * sxi
                    + gB * kAs[h * 16 + j] * stos[h * 16 + j]
                    + gB * kBs[h * 16 + j] * 16384.f;
      const float l = tt * s * rnq * rks[h * 16 + j];
      lg[j] = l;
      mx = fmaxf(mx, l);
    }
    float den = 0.f;
#pragma unroll
    for (int j = 0; j < 16; ++j) { const float ev = expf(lg[j] - mx); lg[j] = ev; den += ev; }
    const float inv = 1.f / den;
    float cs = 0.f;
    float* WVp = ws + OFF_WV + (size_t)(b * 16 + h) * 256 + i * 16;
#pragma unroll
    for (int j = 0; j < 16; ++j) {
      const float aa = lg[j] * inv;
      const int gj = c0 + j;
      WVp[j] = aa * aV[gj * 2 + e];
      cs = fmaf(aa, bV[gj * 2 + e], cs);
    }
    ws[OFF_CST + b * 256 + i * 16 + h] = cs;
  }
}

// K3: fold attention into per-batch bf16 conv weights + constant taps.
__global__ __launch_bounds__(128) void k_weff(const float* __restrict__ w_f,
                                              float* __restrict__ ws) {
  const int b = blockIdx.x >> 7, oc = blockIdx.x & 127;
  const int c = threadIdx.x, blk = c >> 4, j = c & 15;
  const float* WVb = ws + OFF_WV;
  float acc[9];
#pragma unroll
  for (int k = 0; k < 9; ++k) acc[k] = 0.f;
#pragma unroll
  for (int e = 0; e < 2; ++e) {
    const int h = e * 8 + blk;
#pragma unroll
    for (int i = 0; i < 16; ++i) {
      const float coef = WVb[((size_t)(b * 16 + h) * 16 + i) * 16 + j];
      const float* wf = w_f + (size_t)(oc * 256 + i * 16 + h) * 9;
#pragma unroll
      for (int k = 0; k < 9; ++k) acc[k] = fmaf(wf[k], coef, acc[k]);
    }
  }
  unsigned short* wb16 = (unsigned short*)(ws + OFF_WEFF);
#pragma unroll
  for (int k = 0; k < 9; ++k)
    wb16[(((size_t)(b * 9 + k)) * 128 + oc) * 128 + c] = f2bf(acc[k]);

  __shared__ float tp[9][128];
  float tl[9];
#pragma unroll
  for (int k = 0; k < 9; ++k) tl[k] = 0.f;
  const float* cst = ws + OFF_CST + b * 256;
  for (int cc = c; cc < 256; cc += 128) {
    const float cv = cst[cc];
    const float* wf = w_f + (size_t)(oc * 256 + cc) * 9;
#pragma unroll
    for (int k = 0; k < 9; ++k) tl[k] = fmaf(wf[k], cv, tl[k]);
  }
#pragma unroll
  for (int k = 0; k < 9; ++k) tp[k][c] = tl[k];
  __syncthreads();
  for (int s = 64; s > 0; s >>= 1) {
    if (c < s) {
#pragma unroll
      for (int k = 0; k < 9; ++k) tp[k][c] += tp[k][c + s];
    }
    __syncthreads();
  }
  if (c < 9) ws[OFF_T + ((size_t)b * 128 + oc) * 9 + c] = tp[c][0];
}

// K4: weight-stationary MFMA conv. Block = (b, oc-half 64, y-pair).
// A (9 taps x 64 oc x 128 cin bf16 = 144 KiB) staged once in LDS, XOR-swizzled.
__global__ __launch_bounds__(512, 2) void k_conv(const float* __restrict__ xin,
                                                 const float* __restrict__ b_f,
                                                 const float* __restrict__ ws,
                                                 const unsigned short* __restrict__ t2,
                                                 float* __restrict__ out) {
  const int d = blockIdx.x;           // 1024 = 8 b * 2 half * 64 ypair
  const int b    = d & 7;             // batch -> XCD
  const int half = (d >> 3) & 1;
  const int y0   = (d >> 4) * 2;
  const int tid  = threadIdx.x;
  const int oc0h = half * 64;

  __shared__ short8 A_s[9216];        // 147456 B = 144 KiB

  {
    const unsigned short* wsrc = (const unsigned short*)(ws + OFF_WEFF)
        + (size_t)b * 9 * 16384 + (size_t)oc0h * 128;
#pragma unroll
    for (int ii = 0; ii < 18; ++ii) {
      const int idx = ii * 512 + tid;
      const int ch = idx & 15, oc = (idx >> 4) & 63, tap = idx >> 10;
      const short8 v = *(const short8*)(wsrc + ((size_t)tap * 128 + oc) * 128 + ch * 8);
      const int dstb = (tap * 64 + oc) * 256 + ((ch ^ (oc & 15)) << 4);
      *(short8*)((char*)A_s + dstb) = v;
    }
  }
  __syncthreads();

  const int l = tid & 63, w = tid >> 6;
  const int row = w & 1, pxq = w >> 1;
  const int y = y0 + row, px0 = pxq * 32;
  const int lm = l & 15, lh = l >> 4;

  f32x4 acc[4][2];
#pragma unroll
  for (int mt = 0; mt < 4; ++mt) { acc[mt][0] = (f32x4)0.f; acc[mt][1] = (f32x4)0.f; }

  const unsigned short* t2b = t2 + ((size_t)b * H_) * 130 * 128
      + (size_t)(px0 + lm) * 128 + lh * 8;

#pragma unroll
  for (int dy = 0; dy < 3; ++dy) {
    const int yy = y + dy - 1;
    if ((unsigned)yy < 128u) {
      const unsigned short* trow = t2b + (size_t)yy * (130 * 128);
#pragma unroll
      for (int dx = 0; dx < 3; ++dx) {
        const int tap = dy * 3 + dx;
        const unsigned short* tcol = trow + (size_t)dx * 128;
#pragma unroll
        for (int ks = 0; ks < 4; ++ks) {
          const short8 b0 = *(const short8*)(tcol + ks * 32);
          const short8 b1 = *(const short8*)(tcol + 2048 + ks * 32);
#pragma unroll
          for (int mt = 0; mt < 4; ++mt) {
            const int ocl = mt * 16 + lm;
            const int abyte = (tap * 64 + ocl) * 256 + ((((4 * ks + lh) ^ (ocl & 15))) << 4);
            const short8 af = *(const short8*)((const char*)A_s + abyte);
            acc[mt][0] = mfma16(af, b0, acc[mt][0]);
            acc[mt][1] = mfma16(af, b1, acc[mt][1]);
          }
        }
      }
    }
  }

  __syncthreads();
  float* sm = (float*)A_s;   // [2][384]: add, left, right
  if (tid < 256) {
    const int rr = tid >> 7, oc = tid & 127;
    const int yv = y0 + rr;
    const float* Tk = ws + OFF_T + (size_t)(b * 128 + oc) * 9;
    float s = Tk[3] + Tk[4] + Tk[5], sl = Tk[3], sr = Tk[5];
    if (yv >= 1)   { s += Tk[0] + Tk[1] + Tk[2]; sl += Tk[0]; sr += Tk[2]; }
    if (yv <= 126) { s += Tk[6] + Tk[7] + Tk[8]; sl += Tk[6]; sr += Tk[8]; }
    sm[rr * 384 + oc] = s + b_f[oc];
    sm[rr * 384 + 128 + oc] = sl;
    sm[rr * 384 + 256 + oc] = sr;
  }
  __syncthreads();

#pragma unroll
  for (int mt = 0; mt < 4; ++mt)
#pragma unroll
    for (int nt = 0; nt < 2; ++nt) {
      const int px = px0 + nt * 16 + lm;
#pragma unroll
      for (int r = 0; r < 4; ++r) {
        const int oc = oc0h + mt * 16 + lh * 4 + r;
        float add = sm[row * 384 + oc];
        if (px == 0)   add -= sm[row * 384 + 128 + oc];
        if (px == 127) add -= sm[row * 384 + 256 + oc];
        const float z = acc[mt][nt][r] + add;
        const size_t base = ((size_t)(b * C_ + oc)) * HW_ + (size_t)y * W_ + px;
        const float rx = xin[base];
        out[base] = rx + (z >= 0.f ? z : 0.2f * z);
      }
    }
}

// K4 fallback (R2 version): used when ws_size can't hold T2.
__global__ __launch_bounds__(512, 4) void k_conv_fb(const float* __restrict__ xin,
                                                    const float* __restrict__ to,
                                                    const float* __restrict__ b_f,
                                                    const float* __restrict__ ws,
                                                    float* __restrict__ out) {
  const int bid = blockIdx.x;
  const int nb  = (bid & 7) * 128 + (bid >> 3);
  const int b   = nb >> 7;
  const int y   = nb & 127;
  const int tid = threadIdx.x;

  __shared__ f32x4 ldsbuf[3120];
  char* lp = (char*)ldsbuf;

  f32x4 acc[4][2];
#pragma unroll
  for (int mt = 0; mt < 4; ++mt)
#pragma unroll
    for (int nt = 0; nt < 2; ++nt) acc[mt][nt] = (f32x4)0.f;

  const float* tob = to + (size_t)b * C_ * HW_;
  const unsigned short* wb16 =
      (const unsigned short*)(ws + OFF_WEFF) + (size_t)b * 9 * 128 * 128;

  const int l = tid & 63, wv = tid >> 6;
  const int ocb0 = (wv & 1) * 64, pxb0 = (wv >> 1) * 32;
  const int lm = l & 15, lh = l >> 4;

  for (int cb = 0; cb < 128; cb += 64) {
    __syncthreads();
    {
      const int xg = tid & 31, cq = (tid >> 5) & 15;
      const int cbase = cb + cq * 4;
#pragma unroll
      for (int row = 0; row < 3; ++row) {
        const int y_in = y + row - 1;
        const bool yok = ((unsigned)y_in < 128u);
        const float* src = tob + (size_t)cbase * HW_ + (size_t)y_in * W_;
#pragma unroll
        for (int xb = 0; xb < 5; ++xb) {
          const int xi = xb * 32 + xg;
          if (xi < 130) {
            const int x_in = xi - 1;
            const bool ok = yok && ((unsigned)x_in < 128u);
            float f0 = 0.f, f1 = 0.f, f2 = 0.f, f3 = 0.f;
            if (ok) {
              f0 = src[x_in];
              f1 = src[HW_ + x_in];
              f2 = src[2 * HW_ + x_in];
              f3 = src[3 * HW_ + x_in];
            }
            ushort4 pk;
            pk.x = f2bf(f0); pk.y = f2bf(f1); pk.z = f2bf(f2); pk.w = f2bf(f3);
            const int boff = (row * 130 + xi) * 128 + ((cq * 8) ^ ((xi & 7) << 4));
            *(ushort4*)(lp + boff) = pk;
          }
        }
      }
    }
    __syncthreads();

    for (int tap = 0; tap < 9; ++tap) {
      const int dy = tap / 3, dx = tap - dy * 3;
#pragma unroll
      for (int ks = 0; ks < 2; ++ks) {
        short8 bfr[2];
#pragma unroll
        for (int nt = 0; nt < 2; ++nt) {
          const int xi = pxb0 + nt * 16 + lm + dx;
          const int boff = (dy * 130 + xi) * 128 + ((ks * 64 + lh * 16) ^ ((xi & 7) << 4));
          bfr[nt] = *(const short8*)(lp + boff);
        }
        const int cin = cb + ks * 32 + lh * 8;
#pragma unroll
        for (int mt = 0; mt < 4; ++mt) {
          const int oc = ocb0 + mt * 16 + lm;
          const short8 af = *(const short8*)(wb16 + ((size_t)tap * 128 + oc) * 128 + cin);
          acc[mt][0] = mfma16(af, bfr[0], acc[mt][0]);
          acc[mt][1] = mfma16(af, bfr[1], acc[mt][1]);
        }
      }
    }
  }

  __syncthreads();
  float* sAdd = (float*)ldsbuf;
  float* sLft = sAdd + 128;
  float* sRgt = sAdd + 256;
  if (tid < 128) {
    const float* Tk = ws + OFF_T + (size_t)(b * 128 + tid) * 9;
    float s = Tk[3] + Tk[4] + Tk[5], sl = Tk[3], sr = Tk[5];
    if (y >= 1)   { s += Tk[0] + Tk[1] + Tk[2]; sl += Tk[0]; sr += Tk[2]; }
    if (y <= 126) { s += Tk[6] + Tk[7] + Tk[8]; sl += Tk[6]; sr += Tk[8]; }
    sAdd[tid] = s + b_f[tid]; sLft[tid] = sl; sRgt[tid] = sr;
  }
  __syncthreads();

#pragma unroll
  for (int mt = 0; mt < 4; ++mt)
#pragma unroll
    for (int nt = 0; nt < 2; ++nt) {
      const int px = pxb0 + nt * 16 + lm;
#pragma unroll
      for (int r = 0; r < 4; ++r) {
        const int oc = ocb0 + mt * 16 + lh * 4 + r;
        float add = sAdd[oc];
        if (px == 0)   add -= sLft[oc];
        if (px == 127) add -= sRgt[oc];
        const float z = acc[mt][nt][r] + add;
        const size_t base = ((size_t)(b * C_ + oc)) * HW_ + (size_t)y * W_ + px;
        const float rx = xin[base];
        out[base] = rx + (z >= 0.f ? z : 0.2f * z);
      }
    }
}

extern "C" void kernel_launch(void* const* d_in, const int* in_sizes, int n_in,
                              void* d_out, int out_size, void* d_ws, size_t ws_size,
                              hipStream_t stream) {
  (void)in_sizes; (void)n_in; (void)out_size;
  const float* x    = (const float*)d_in[0];
  const float* to   = (const float*)d_in[1];
  const float* t    = (const float*)d_in[2];
  const float* w_r1 = (const float*)d_in[3];
  const float* b_r1 = (const float*)d_in[4];
  const float* w_r2 = (const float*)d_in[5];
  const float* b_r2 = (const float*)d_in[6];
  const float* w_r3 = (const float*)d_in[7];
  const float* b_r3 = (const float*)d_in[8];
  const float* w_t1 = (const float*)d_in[9];
  const float* b_t1 = (const float*)d_in[10];
  const float* w_t2 = (const float*)d_in[11];
  const float* b_t2 = (const float*)d_in[12];
  const float* w_t3 = (const float*)d_in[13];
  const float* b_t3 = (const float*)d_in[14];
  const float* w_f  = (const float*)d_in[15];
  const float* b_f  = (const float*)d_in[16];
  float* ws  = (float*)d_ws;
  float* out = (float*)d_out;
  unsigned short* t2 = (unsigned short*)(ws + OFF_T2F);
  const bool fast = (ws_size >= WS_NEED);

  k_reduce<<<1024, 256, 0, stream>>>(x, to, ws);
  k_redB<<<80, 256, 0, stream>>>(ws);
  if (fast) k_tr<<<2048, 256, 0, stream>>>(to, t2);
  k_attn<<<8, 256, 0, stream>>>(t, w_r1, b_r1, w_r2, b_r2, w_r3, b_r3,
                                w_t1, b_t1, w_t2, b_t2, w_t3, b_t3, ws);
  k_weff<<<1024, 128, 0, stream>>>(w_f, ws);
  if (fast) k_conv<<<1024, 512, 0, stream>>>(x, b_f, ws, t2, out);
  else      k_conv_fb<<<1024, 512, 0, stream>>>(x, to, b_f, ws, out);
}